// Round 9
// baseline (106.359 us; speedup 1.0000x reference)
//
#include <hip/hip_runtime.h>
#include <hip/hip_bf16.h>

// DCRNN single-step, algebraically reduced (proven rounds 2-8):
//   xm = x * mask
//   Z  = sigmoid(xm @ WzE + bz),  WzE = w_z[0,0][:256] + w_z[1,0][:256]
//   Ht = tanh   (xm @ WhE + bh)
//   h  = elu((1 - Z) * Ht)         // H=0 -> Z*H drops; R/w_r/b_r dead; edges dead
//   out = h @ w_lin.T + b_lin      // f32 output
//
// Split-bf16 MFMA: x = xhi + xlo; W hi-only (R7-proven, absmax 0.0156 vs thr 0.0497).
// Round-9: persistent structure — 512 blocks grid-stride over row-tiles; each wave
// holds its 32 gate-weight fragments in REGISTERS for the whole kernel (loop-
// invariant, compiler can't tier-chase them away); out-weights in LDS once/block;
// next tile's x/mask prefetched into regs during compute (T14). Gate inner loop is
// pure LDS+MFMA. Arithmetic & accumulation order identical to R8 -> same absmax.

typedef __attribute__((ext_vector_type(8))) short bf16x8;   // 8 bf16 = 4 VGPR
typedef __attribute__((ext_vector_type(4))) float f32x4;

constexpr int N_ROWS = 50000;
constexpr int CIN  = 256;
constexpr int COUT = 64;
constexpr int BM   = 32;
constexpr int NTILES = (N_ROWS + BM - 1) / BM;   // 1563
constexpr int GRID = 512;

__device__ inline unsigned short f2bf(float f) {          // RNE f32 -> bf16 bits
    union { float f; unsigned u; } v; v.f = f;
    unsigned r = v.u + 0x7fffu + ((v.u >> 16) & 1u);
    return (unsigned short)(r >> 16);
}
__device__ inline float bf2f(unsigned short b) {
    union { unsigned u; float f; } v; v.u = ((unsigned)b) << 16;
    return v.f;
}
__device__ inline f32x4 mfma16(bf16x8 a, bf16x8 b, f32x4 c) {
    return __builtin_amdgcn_mfma_f32_16x16x32_bf16(a, b, c, 0, 0, 0);
}

// ---------------- weight prep: B-fragment-ordered bf16 (hi only; proven R7/R8) ----------------
// Fragment f holds, for lane l, 8 bf16: B[k = kb*32 + (l>>4)*8 + j][n = nf*16 + (l&15)]
// gate frags f = (g*16 + nf)*8 + kb   g:0=Z,1=H   nf<16 kb<8   -> [0,256)
// out  frags f = 256 + nf*8 + kb      nf<4                     -> [256,288)
__global__ __launch_bounds__(256) void prep_frags(
    const float* __restrict__ wz, const float* __restrict__ wh,
    const float* __restrict__ wlin, unsigned short* __restrict__ ws)
{
    int t = blockIdx.x * 256 + threadIdx.x;
    int frag = t >> 6, lane = t & 63;
    if (frag >= 288) return;
    int g16 = lane & 15, kg = lane >> 4;
    unsigned short vals[8];
    if (frag < 256) {
        int kb = frag & 7, nf = (frag >> 3) & 15, g = frag >> 7;
        const float* wsrc = g ? wh : wz;
        int n = nf * 16 + g16;
        #pragma unroll
        for (int j = 0; j < 8; ++j) {
            int k = kb * 32 + kg * 8 + j;
            float v = wsrc[k * 256 + n] + wsrc[131072 + k * 256 + n];  // tap0 + tap1
            vals[j] = f2bf(v);
        }
    } else {
        int f = frag - 256;
        int kb = f & 7, nf = f >> 3;
        int n = nf * 16 + g16;                       // output column o
        #pragma unroll
        for (int j = 0; j < 8; ++j) {
            int k = kb * 32 + kg * 8 + j;
            vals[j] = f2bf(wlin[n * 256 + k]);       // B[k][o] = w_lin[o][k]
        }
    }
    unsigned short* dst = ws + (size_t)frag * 512 + lane * 8;
    #pragma unroll
    for (int j = 0; j < 8; ++j) dst[j] = vals[j];
}

__device__ inline bf16x8 ldfrag(const unsigned short* wf, int frag, int lane) {
    return *reinterpret_cast<const bf16x8*>(wf + (size_t)frag * 512 + lane * 8);
}

// ---------------- persistent fused MFMA kernel (BM=32, 8 waves, weights-in-regs) ----------------
__global__ __launch_bounds__(512, 2) void dcrnn_persist(
    const float* __restrict__ x, const float* __restrict__ mask,
    const unsigned short* __restrict__ wf,
    const float* __restrict__ bz, const float* __restrict__ bh,
    const float* __restrict__ blin, float* __restrict__ out)
{
    __shared__ char smem[65536];               // [0,32K): x hi/lo tile, later h; [32K,64K): out weights
    char* AhiB = smem;                         // 16 KB, XOR-swizzled bf16 x_hi (32x256)
    char* AloB = smem + 16384;                 // 16 KB, XOR-swizzled bf16 x_lo
    unsigned short* owLDS = reinterpret_cast<unsigned short*>(smem + 32768);

    const int tid = threadIdx.x, lane = tid & 63, wv = tid >> 6;   // wv in [0,8)
    const int l16 = lane & 15, lk = lane >> 4;
    const int nf0 = wv * 2;                    // this wave's 2 nf slices (cols wv*32..+32)

    // ---- gate weights -> registers, ONCE (128 VGPR, live whole kernel) ----
    bf16x8 wZ[2][8], wH[2][8];
    #pragma unroll
    for (int nfi = 0; nfi < 2; ++nfi)
        #pragma unroll
        for (int kb = 0; kb < 8; ++kb) {
            wZ[nfi][kb] = ldfrag(wf, (nf0 + nfi) * 8 + kb, lane);
            wH[nfi][kb] = ldfrag(wf, (16 + nf0 + nfi) * 8 + kb, lane);
        }
    // ---- out weights -> LDS, ONCE (32 KB linear copy) ----
    {
        const uint4* src = reinterpret_cast<const uint4*>(wf + 256 * 512);
        uint4* dst = reinterpret_cast<uint4*>(owLDS);
        #pragma unroll
        for (int i = 0; i < 4; ++i) dst[i * 512 + tid] = src[i * 512 + tid];
    }
    // ---- per-lane bias constants (hoisted out of the tile loop) ----
    float bzv[2], bhv[2];
    #pragma unroll
    for (int nfi = 0; nfi < 2; ++nfi) {
        int col = wv * 32 + nfi * 16 + l16;
        bzv[nfi] = bz[col]; bhv[nfi] = bh[col];
    }
    const int ocol = (wv & 3) * 16 + l16;
    const float bo = blin[ocol];
    const int mo = wv >> 2;

    // ---- prefetch first tile's x/mask into registers ----
    int t = blockIdx.x;
    float4 px[4], pm[4];
    #pragma unroll
    for (int it = 0; it < 4; ++it) {
        int s = it * 512 + tid, r = s >> 6, c4 = s & 63;
        int row = t * BM + r;
        px[it] = make_float4(0.f, 0.f, 0.f, 0.f); pm[it] = px[it];
        if (row < N_ROWS) {
            px[it] = reinterpret_cast<const float4*>(x    + (size_t)row * CIN)[c4];
            pm[it] = reinterpret_cast<const float4*>(mask + (size_t)row * CIN)[c4];
        }
    }
    __syncthreads();   // owLDS copy ordered before any consumer

    for (; t < NTILES; t += GRID) {
        // ---- convert prefetched regs -> hi/lo bf16 in LDS (swizzled, proven layout) ----
        #pragma unroll
        for (int it = 0; it < 4; ++it) {
            int s = it * 512 + tid, r = s >> 6, c4 = s & 63;
            float v0 = px[it].x * pm[it].x, v1 = px[it].y * pm[it].y;
            float v2 = px[it].z * pm[it].z, v3 = px[it].w * pm[it].w;
            unsigned short h0 = f2bf(v0), h1 = f2bf(v1), h2 = f2bf(v2), h3 = f2bf(v3);
            unsigned short l0 = f2bf(v0 - bf2f(h0)), l1 = f2bf(v1 - bf2f(h1));
            unsigned short l2 = f2bf(v2 - bf2f(h2)), l3 = f2bf(v3 - bf2f(h3));
            int byte = ((r * CIN + c4 * 4) * 2) ^ ((r & 7) << 4);     // T2 swizzle
            *reinterpret_cast<ushort4*>(AhiB + byte) = make_ushort4(h0, h1, h2, h3);
            *reinterpret_cast<ushort4*>(AloB + byte) = make_ushort4(l0, l1, l2, l3);
        }
        // ---- issue next tile's prefetch (in flight across the whole compute) ----
        int tn = t + GRID;
        if (tn < NTILES) {
            #pragma unroll
            for (int it = 0; it < 4; ++it) {
                int s = it * 512 + tid, r = s >> 6, c4 = s & 63;
                int row = tn * BM + r;
                px[it] = make_float4(0.f, 0.f, 0.f, 0.f); pm[it] = px[it];
                if (row < N_ROWS) {
                    px[it] = reinterpret_cast<const float4*>(x    + (size_t)row * CIN)[c4];
                    pm[it] = reinterpret_cast<const float4*>(mask + (size_t)row * CIN)[c4];
                }
            }
        }
        __syncthreads();   // staged tile visible

        // ---- gate GEMMs: pure LDS + MFMA (weights in regs) ----
        f32x4 accZ[2][2], accH[2][2];          // [nfi][m]
        #pragma unroll
        for (int nfi = 0; nfi < 2; ++nfi)
            #pragma unroll
            for (int m = 0; m < 2; ++m) {
                accZ[nfi][m] = (f32x4){0.f, 0.f, 0.f, 0.f};
                accH[nfi][m] = (f32x4){0.f, 0.f, 0.f, 0.f};
            }
        #pragma unroll
        for (int kb = 0; kb < 8; ++kb) {
            bf16x8 ah[2], al[2];
            int koff = kb * 32 + lk * 8;
            #pragma unroll
            for (int m = 0; m < 2; ++m) {
                int row = m * 16 + l16;
                int byte = ((row * CIN + koff) * 2) ^ ((row & 7) << 4);
                ah[m] = *reinterpret_cast<const bf16x8*>(AhiB + byte);
                al[m] = *reinterpret_cast<const bf16x8*>(AloB + byte);
            }
            #pragma unroll
            for (int nfi = 0; nfi < 2; ++nfi)
                #pragma unroll
                for (int m = 0; m < 2; ++m) {
                    accZ[nfi][m] = mfma16(ah[m], wZ[nfi][kb], accZ[nfi][m]);
                    accZ[nfi][m] = mfma16(al[m], wZ[nfi][kb], accZ[nfi][m]);
                    accH[nfi][m] = mfma16(ah[m], wH[nfi][kb], accH[nfi][m]);
                    accH[nfi][m] = mfma16(al[m], wH[nfi][kb], accH[nfi][m]);
                }
        }
        __syncthreads();   // all waves done reading x before h overwrites smem

        // ---- nonlinearities + GRU blend; h -> LDS as (bf16 bits << 16) u32 ----
        #pragma unroll
        for (int nfi = 0; nfi < 2; ++nfi) {
            int col = wv * 32 + nfi * 16 + l16;
            #pragma unroll
            for (int m = 0; m < 2; ++m) {
                #pragma unroll
                for (int i = 0; i < 4; ++i) {
                    float z  = 1.f / (1.f + __expf(-(accZ[nfi][m][i] + bzv[nfi])));
                    float tt = __expf(2.f * (accH[nfi][m][i] + bhv[nfi]));
                    float th = (tt - 1.f) / (tt + 1.f);
                    float H  = (1.f - z) * th;
                    float h  = (H > 0.f) ? H : (__expf(H) - 1.f);   // elu(alpha=1)
                    int row = m * 16 + lk * 4 + i;                  // C/D: row=(lane>>4)*4+reg
                    unsigned pk = ((unsigned)f2bf(h)) << 16;
                    int byte = (row * 1024 + col * 4) ^ ((row & 7) << 4);
                    *reinterpret_cast<unsigned*>(smem + byte) = pk;
                }
            }
        }
        __syncthreads();

        // ---- out GEMM: wave wv -> rows [mo*16,+16), out-cols [(wv&3)*16,+16) ----
        f32x4 accO = (f32x4){0.f, 0.f, 0.f, 0.f};
        #pragma unroll
        for (int kb = 0; kb < 8; ++kb) {
            bf16x8 cb = *reinterpret_cast<const bf16x8*>(
                owLDS + (size_t)((wv & 3) * 8 + kb) * 512 + lane * 8);
            int row = mo * 16 + l16;
            int e0  = kb * 32 + lk * 8;
            int b0  = (row * 1024 + e0 * 4)      ^ ((row & 7) << 4);
            int b1  = (row * 1024 + e0 * 4 + 16) ^ ((row & 7) << 4);
            uint4 p0 = *reinterpret_cast<const uint4*>(smem + b0);
            uint4 p1 = *reinterpret_cast<const uint4*>(smem + b1);
            bf16x8 ha;
            ha[0] = (short)(p0.x >> 16); ha[1] = (short)(p0.y >> 16);
            ha[2] = (short)(p0.z >> 16); ha[3] = (short)(p0.w >> 16);
            ha[4] = (short)(p1.x >> 16); ha[5] = (short)(p1.y >> 16);
            ha[6] = (short)(p1.z >> 16); ha[7] = (short)(p1.w >> 16);
            accO = mfma16(ha, cb, accO);
        }
        #pragma unroll
        for (int i = 0; i < 4; ++i) {
            int row = t * BM + mo * 16 + lk * 4 + i;
            if (row < N_ROWS) out[(size_t)row * COUT + ocol] = accO[i] + bo;
        }
        __syncthreads();   // h fully consumed before next tile's staging write
    }
}

// ---------------- fallback: round-2 f32 kernel (proven; used only if ws too small) ----------------
__global__ __launch_bounds__(256) void fallback_f32(
    const float* __restrict__ x, const float* __restrict__ mask,
    const float* __restrict__ wzr, const float* __restrict__ whr,
    const float* __restrict__ bz, const float* __restrict__ bh,
    const float* __restrict__ wlinr, const float* __restrict__ blin,
    float* __restrict__ out)
{
    __shared__ float xm[32][CIN];
    const int tid = threadIdx.x;
    const int row0 = blockIdx.x * 32;
    #pragma unroll
    for (int it = 0; it < 8; ++it) {
        int idx = it * 256 + tid;
        int r = idx >> 6, c4 = idx & 63, row = row0 + r;
        float4 v = make_float4(0.f, 0.f, 0.f, 0.f);
        if (row < N_ROWS) {
            float4 a = reinterpret_cast<const float4*>(x    + (size_t)row * CIN)[c4];
            float4 m = reinterpret_cast<const float4*>(mask + (size_t)row * CIN)[c4];
            v = make_float4(a.x * m.x, a.y * m.y, a.z * m.z, a.w * m.w);
        }
        reinterpret_cast<float4*>(&xm[r][0])[c4] = v;
    }
    __syncthreads();
    const int j0 = (tid & 63) * 4, r0 = (tid >> 6) * 8;
    float accz[4][8], acch[4][8];
    #pragma unroll
    for (int c = 0; c < 4; ++c)
        #pragma unroll
        for (int r = 0; r < 8; ++r) { accz[c][r] = 0.f; acch[c][r] = 0.f; }
    for (int k = 0; k < CIN; k += 4) {
        float4 wz4[4], wh4[4];
        #pragma unroll
        for (int kk = 0; kk < 4; ++kk) {
            float4 a0 = *reinterpret_cast<const float4*>(&wzr[(k + kk) * 256 + j0]);
            float4 a1 = *reinterpret_cast<const float4*>(&wzr[131072 + (k + kk) * 256 + j0]);
            wz4[kk] = make_float4(a0.x + a1.x, a0.y + a1.y, a0.z + a1.z, a0.w + a1.w);
            float4 b0 = *reinterpret_cast<const float4*>(&whr[(k + kk) * 256 + j0]);
            float4 b1 = *reinterpret_cast<const float4*>(&whr[131072 + (k + kk) * 256 + j0]);
            wh4[kk] = make_float4(b0.x + b1.x, b0.y + b1.y, b0.z + b1.z, b0.w + b1.w);
        }
        #pragma unroll
        for (int r = 0; r < 8; ++r) {
            float4 xv = *reinterpret_cast<const float4*>(&xm[r0 + r][k]);
            float xk[4] = {xv.x, xv.y, xv.z, xv.w};
            float wzc[4][4] = {{wz4[0].x,wz4[0].y,wz4[0].z,wz4[0].w},{wz4[1].x,wz4[1].y,wz4[1].z,wz4[1].w},
                               {wz4[2].x,wz4[2].y,wz4[2].z,wz4[2].w},{wz4[3].x,wz4[3].y,wz4[3].z,wz4[3].w}};
            float whc[4][4] = {{wh4[0].x,wh4[0].y,wh4[0].z,wh4[0].w},{wh4[1].x,wh4[1].y,wh4[1].z,wh4[1].w},
                               {wh4[2].x,wh4[2].y,wh4[2].z,wh4[2].w},{wh4[3].x,wh4[3].y,wh4[3].z,wh4[3].w}};
            #pragma unroll
            for (int kk = 0; kk < 4; ++kk)
                #pragma unroll
                for (int c = 0; c < 4; ++c) {
                    accz[c][r] = fmaf(xk[kk], wzc[kk][c], accz[c][r]);
                    acch[c][r] = fmaf(xk[kk], whc[kk][c], acch[c][r]);
                }
        }
    }
    float bzj[4], bhj[4];
    #pragma unroll
    for (int c = 0; c < 4; ++c) { bzj[c] = bz[j0 + c]; bhj[c] = bh[j0 + c]; }
    __syncthreads();
    #pragma unroll
    for (int r = 0; r < 8; ++r) {
        float hc[4];
        #pragma unroll
        for (int c = 0; c < 4; ++c) {
            float z  = 1.f / (1.f + expf(-(accz[c][r] + bzj[c])));
            float ht = tanhf(acch[c][r] + bhj[c]);
            float H  = (1.f - z) * ht;
            hc[c] = (H > 0.f) ? H : expm1f(H);
        }
        *reinterpret_cast<float4*>(&xm[r0 + r][j0]) = make_float4(hc[0], hc[1], hc[2], hc[3]);
    }
    __syncthreads();
    const int o = tid & 63;
    float acc[8];
    #pragma unroll
    for (int r = 0; r < 8; ++r) acc[r] = 0.f;
    for (int k = 0; k < CIN; k += 4) {
        float4 wv4 = *reinterpret_cast<const float4*>(&wlinr[o * 256 + k]);
        #pragma unroll
        for (int r = 0; r < 8; ++r) {
            float4 hv = *reinterpret_cast<const float4*>(&xm[r0 + r][k]);
            acc[r] = fmaf(hv.x, wv4.x, acc[r]);
            acc[r] = fmaf(hv.y, wv4.y, acc[r]);
            acc[r] = fmaf(hv.z, wv4.z, acc[r]);
            acc[r] = fmaf(hv.w, wv4.w, acc[r]);
        }
    }
    float bo = blin[o];
    #pragma unroll
    for (int r = 0; r < 8; ++r) {
        int row = row0 + r0 + r;
        if (row < N_ROWS) out[(size_t)row * COUT + o] = acc[r] + bo;
    }
}

extern "C" void kernel_launch(void* const* d_in, const int* in_sizes, int n_in,
                              void* d_out, int out_size, void* d_ws, size_t ws_size,
                              hipStream_t stream)
{
    const float* x    = (const float*)d_in[0];
    // d_in[1] edge_index, d_in[2] edge_weight: unused (K=1 identity term only)
    const float* mask = (const float*)d_in[3];
    const float* wz   = (const float*)d_in[4];
    const float* bz   = (const float*)d_in[5];
    // d_in[6] w_r, d_in[7] b_r: dead (H=0 -> reset gate unused)
    const float* wh   = (const float*)d_in[8];
    const float* bh   = (const float*)d_in[9];
    const float* wlin = (const float*)d_in[10];
    const float* blin = (const float*)d_in[11];
    float* outf = (float*)d_out;

    const size_t ws_need = 288 * 1024;   // 288 frags x 1 KB
    if (ws_size >= ws_need) {
        unsigned short* wsf = (unsigned short*)d_ws;
        prep_frags<<<72, 256, 0, stream>>>(wz, wh, wlin, wsf);
        dcrnn_persist<<<GRID, 512, 0, stream>>>(
            x, mask, wsf, bz, bh, blin, outf);
    } else {
        fallback_f32<<<(N_ROWS + 31) / 32, 256, 0, stream>>>(
            x, mask, wz, wh, bz, bh, wlin, blin, outf);
    }
}

// Round 10
// 88.058 us; speedup vs baseline: 1.2078x; 1.2078x over previous
//
#include <hip/hip_runtime.h>
#include <hip/hip_bf16.h>

// DCRNN single-step, algebraically reduced (proven rounds 2-9):
//   xm = x * mask
//   Z  = sigmoid(xm @ WzE + bz),  WzE = w_z[0,0][:256] + w_z[1,0][:256]
//   Ht = tanh   (xm @ WhE + bh)
//   h  = elu((1 - Z) * Ht)         // H=0 -> Z*H drops; R/w_r/b_r dead; edges dead
//   out = h @ w_lin.T + b_lin      // f32 output
//
// Split-bf16 MFMA: x = xhi + xlo; W hi-only (absmax 0.0156 vs thr 0.0497, R7-R9).
// Round-10: R9 persistent structure + amdgpu_waves_per_eu(2,2) PIN. R6/R8/R9 all
// showed the allocator tier-chasing occupancy and deleting/spilling register state
// (R9: VGPR=128 + 36 MB scratch writes). Pinning min=max=2 waves/EU gives a firm
// 256-VGPR budget so the 32 weight fragments (128 VGPR) stay resident. Peak
// pressure trimmed: x/mask prefetch depth halved; prefetch issued after the
// staging barrier (drain overlaps gate compute, not the barrier).
// Arithmetic & accumulation order identical to R9 -> absmax exactly 0.015625.

typedef __attribute__((ext_vector_type(8))) short bf16x8;   // 8 bf16 = 4 VGPR
typedef __attribute__((ext_vector_type(4))) float f32x4;

constexpr int N_ROWS = 50000;
constexpr int CIN  = 256;
constexpr int COUT = 64;
constexpr int BM   = 32;
constexpr int NTILES = (N_ROWS + BM - 1) / BM;   // 1563
constexpr int GRID = 512;

__device__ inline unsigned short f2bf(float f) {          // RNE f32 -> bf16 bits
    union { float f; unsigned u; } v; v.f = f;
    unsigned r = v.u + 0x7fffu + ((v.u >> 16) & 1u);
    return (unsigned short)(r >> 16);
}
__device__ inline float bf2f(unsigned short b) {
    union { unsigned u; float f; } v; v.u = ((unsigned)b) << 16;
    return v.f;
}
__device__ inline f32x4 mfma16(bf16x8 a, bf16x8 b, f32x4 c) {
    return __builtin_amdgcn_mfma_f32_16x16x32_bf16(a, b, c, 0, 0, 0);
}

// ---------------- weight prep: B-fragment-ordered bf16 (hi only; proven R7-R9) ----------------
// Fragment f holds, for lane l, 8 bf16: B[k = kb*32 + (l>>4)*8 + j][n = nf*16 + (l&15)]
// gate frags f = (g*16 + nf)*8 + kb   g:0=Z,1=H   nf<16 kb<8   -> [0,256)
// out  frags f = 256 + nf*8 + kb      nf<4                     -> [256,288)
__global__ __launch_bounds__(256) void prep_frags(
    const float* __restrict__ wz, const float* __restrict__ wh,
    const float* __restrict__ wlin, unsigned short* __restrict__ ws)
{
    int t = blockIdx.x * 256 + threadIdx.x;
    int frag = t >> 6, lane = t & 63;
    if (frag >= 288) return;
    int g16 = lane & 15, kg = lane >> 4;
    unsigned short vals[8];
    if (frag < 256) {
        int kb = frag & 7, nf = (frag >> 3) & 15, g = frag >> 7;
        const float* wsrc = g ? wh : wz;
        int n = nf * 16 + g16;
        #pragma unroll
        for (int j = 0; j < 8; ++j) {
            int k = kb * 32 + kg * 8 + j;
            float v = wsrc[k * 256 + n] + wsrc[131072 + k * 256 + n];  // tap0 + tap1
            vals[j] = f2bf(v);
        }
    } else {
        int f = frag - 256;
        int kb = f & 7, nf = f >> 3;
        int n = nf * 16 + g16;                       // output column o
        #pragma unroll
        for (int j = 0; j < 8; ++j) {
            int k = kb * 32 + kg * 8 + j;
            vals[j] = f2bf(wlin[n * 256 + k]);       // B[k][o] = w_lin[o][k]
        }
    }
    unsigned short* dst = ws + (size_t)frag * 512 + lane * 8;
    #pragma unroll
    for (int j = 0; j < 8; ++j) dst[j] = vals[j];
}

__device__ inline bf16x8 ldfrag(const unsigned short* wf, int frag, int lane) {
    return *reinterpret_cast<const bf16x8*>(wf + (size_t)frag * 512 + lane * 8);
}

// ---------------- persistent fused MFMA kernel (weights-in-regs, waves/EU pinned) ----------------
__global__ __launch_bounds__(512)
__attribute__((amdgpu_waves_per_eu(2, 2)))
void dcrnn_persist(
    const float* __restrict__ x, const float* __restrict__ mask,
    const unsigned short* __restrict__ wf,
    const float* __restrict__ bz, const float* __restrict__ bh,
    const float* __restrict__ blin, float* __restrict__ out)
{
    __shared__ char smem[65536];               // [0,32K): x hi/lo tile, later h; [32K,64K): out weights
    char* AhiB = smem;                         // 16 KB, XOR-swizzled bf16 x_hi (32x256)
    char* AloB = smem + 16384;                 // 16 KB, XOR-swizzled bf16 x_lo
    unsigned short* owLDS = reinterpret_cast<unsigned short*>(smem + 32768);

    const int tid = threadIdx.x, lane = tid & 63, wv = tid >> 6;   // wv in [0,8)
    const int l16 = lane & 15, lk = lane >> 4;
    const int nf0 = wv * 2;                    // this wave's 2 nf slices (cols wv*32..+32)

    // ---- gate weights -> registers, ONCE (128 VGPR, live whole kernel) ----
    bf16x8 wZ[2][8], wH[2][8];
    #pragma unroll
    for (int nfi = 0; nfi < 2; ++nfi)
        #pragma unroll
        for (int kb = 0; kb < 8; ++kb) {
            wZ[nfi][kb] = ldfrag(wf, (nf0 + nfi) * 8 + kb, lane);
            wH[nfi][kb] = ldfrag(wf, (16 + nf0 + nfi) * 8 + kb, lane);
        }
    // ---- out weights -> LDS, ONCE (32 KB linear copy) ----
    {
        const uint4* src = reinterpret_cast<const uint4*>(wf + 256 * 512);
        uint4* dst = reinterpret_cast<uint4*>(owLDS);
        #pragma unroll
        for (int i = 0; i < 4; ++i) dst[i * 512 + tid] = src[i * 512 + tid];
    }
    // ---- per-lane bias constants (hoisted out of the tile loop) ----
    float bzv[2], bhv[2];
    #pragma unroll
    for (int nfi = 0; nfi < 2; ++nfi) {
        int col = wv * 32 + nfi * 16 + l16;
        bzv[nfi] = bz[col]; bhv[nfi] = bh[col];
    }
    const int ocol = (wv & 3) * 16 + l16;
    const float bo = blin[ocol];
    const int mo = wv >> 2;

    // ---- prefetch first tile's x/mask half (it=0,1) into registers ----
    int t = blockIdx.x;
    float4 px[2], pm[2];
    #pragma unroll
    for (int it = 0; it < 2; ++it) {
        int s = it * 512 + tid, r = s >> 6, c4 = s & 63;
        int row = t * BM + r;
        px[it] = make_float4(0.f, 0.f, 0.f, 0.f); pm[it] = px[it];
        if (row < N_ROWS) {
            px[it] = reinterpret_cast<const float4*>(x    + (size_t)row * CIN)[c4];
            pm[it] = reinterpret_cast<const float4*>(mask + (size_t)row * CIN)[c4];
        }
    }
    __syncthreads();   // owLDS copy ordered before any consumer

    for (; t < NTILES; t += GRID) {
        // ---- stage: it=0,1 from prefetched regs; it=2,3 loaded directly ----
        #pragma unroll
        for (int it = 0; it < 4; ++it) {
            int s = it * 512 + tid, r = s >> 6, c4 = s & 63;
            float4 xv, mv;
            if (it < 2) { xv = px[it]; mv = pm[it]; }
            else {
                int row = t * BM + r;
                xv = make_float4(0.f, 0.f, 0.f, 0.f); mv = xv;
                if (row < N_ROWS) {
                    xv = reinterpret_cast<const float4*>(x    + (size_t)row * CIN)[c4];
                    mv = reinterpret_cast<const float4*>(mask + (size_t)row * CIN)[c4];
                }
            }
            float v0 = xv.x * mv.x, v1 = xv.y * mv.y, v2 = xv.z * mv.z, v3 = xv.w * mv.w;
            unsigned short h0 = f2bf(v0), h1 = f2bf(v1), h2 = f2bf(v2), h3 = f2bf(v3);
            unsigned short l0 = f2bf(v0 - bf2f(h0)), l1 = f2bf(v1 - bf2f(h1));
            unsigned short l2 = f2bf(v2 - bf2f(h2)), l3 = f2bf(v3 - bf2f(h3));
            int byte = ((r * CIN + c4 * 4) * 2) ^ ((r & 7) << 4);     // T2 swizzle
            *reinterpret_cast<ushort4*>(AhiB + byte) = make_ushort4(h0, h1, h2, h3);
            *reinterpret_cast<ushort4*>(AloB + byte) = make_ushort4(l0, l1, l2, l3);
        }
        __syncthreads();   // staged tile visible

        // ---- issue next tile's half-prefetch NOW (in flight under gate compute) ----
        int tn = t + GRID;
        if (tn < NTILES) {
            #pragma unroll
            for (int it = 0; it < 2; ++it) {
                int s = it * 512 + tid, r = s >> 6, c4 = s & 63;
                int row = tn * BM + r;
                px[it] = make_float4(0.f, 0.f, 0.f, 0.f); pm[it] = px[it];
                if (row < N_ROWS) {
                    px[it] = reinterpret_cast<const float4*>(x    + (size_t)row * CIN)[c4];
                    pm[it] = reinterpret_cast<const float4*>(mask + (size_t)row * CIN)[c4];
                }
            }
        }

        // ---- gate GEMMs: pure LDS + MFMA (weights in regs) ----
        f32x4 accZ[2][2], accH[2][2];          // [nfi][m]
        #pragma unroll
        for (int nfi = 0; nfi < 2; ++nfi)
            #pragma unroll
            for (int m = 0; m < 2; ++m) {
                accZ[nfi][m] = (f32x4){0.f, 0.f, 0.f, 0.f};
                accH[nfi][m] = (f32x4){0.f, 0.f, 0.f, 0.f};
            }
        #pragma unroll
        for (int kb = 0; kb < 8; ++kb) {
            bf16x8 ah[2], al[2];
            int koff = kb * 32 + lk * 8;
            #pragma unroll
            for (int m = 0; m < 2; ++m) {
                int row = m * 16 + l16;
                int byte = ((row * CIN + koff) * 2) ^ ((row & 7) << 4);
                ah[m] = *reinterpret_cast<const bf16x8*>(AhiB + byte);
                al[m] = *reinterpret_cast<const bf16x8*>(AloB + byte);
            }
            #pragma unroll
            for (int nfi = 0; nfi < 2; ++nfi)
                #pragma unroll
                for (int m = 0; m < 2; ++m) {
                    accZ[nfi][m] = mfma16(ah[m], wZ[nfi][kb], accZ[nfi][m]);
                    accZ[nfi][m] = mfma16(al[m], wZ[nfi][kb], accZ[nfi][m]);
                    accH[nfi][m] = mfma16(ah[m], wH[nfi][kb], accH[nfi][m]);
                    accH[nfi][m] = mfma16(al[m], wH[nfi][kb], accH[nfi][m]);
                }
        }
        __syncthreads();   // all waves done reading x before h overwrites smem

        // ---- nonlinearities + GRU blend; h -> LDS as (bf16 bits << 16) u32 ----
        #pragma unroll
        for (int nfi = 0; nfi < 2; ++nfi) {
            int col = wv * 32 + nfi * 16 + l16;
            #pragma unroll
            for (int m = 0; m < 2; ++m) {
                #pragma unroll
                for (int i = 0; i < 4; ++i) {
                    float z  = 1.f / (1.f + __expf(-(accZ[nfi][m][i] + bzv[nfi])));
                    float tt = __expf(2.f * (accH[nfi][m][i] + bhv[nfi]));
                    float th = (tt - 1.f) / (tt + 1.f);
                    float H  = (1.f - z) * th;
                    float h  = (H > 0.f) ? H : (__expf(H) - 1.f);   // elu(alpha=1)
                    int row = m * 16 + lk * 4 + i;                  // C/D: row=(lane>>4)*4+reg
                    unsigned pk = ((unsigned)f2bf(h)) << 16;
                    int byte = (row * 1024 + col * 4) ^ ((row & 7) << 4);
                    *reinterpret_cast<unsigned*>(smem + byte) = pk;
                }
            }
        }
        __syncthreads();

        // ---- out GEMM: wave wv -> rows [mo*16,+16), out-cols [(wv&3)*16,+16) ----
        f32x4 accO = (f32x4){0.f, 0.f, 0.f, 0.f};
        #pragma unroll
        for (int kb = 0; kb < 8; ++kb) {
            bf16x8 cb = *reinterpret_cast<const bf16x8*>(
                owLDS + (size_t)((wv & 3) * 8 + kb) * 512 + lane * 8);
            int row = mo * 16 + l16;
            int e0  = kb * 32 + lk * 8;
            int b0  = (row * 1024 + e0 * 4)      ^ ((row & 7) << 4);
            int b1  = (row * 1024 + e0 * 4 + 16) ^ ((row & 7) << 4);
            uint4 p0 = *reinterpret_cast<const uint4*>(smem + b0);
            uint4 p1 = *reinterpret_cast<const uint4*>(smem + b1);
            bf16x8 ha;
            ha[0] = (short)(p0.x >> 16); ha[1] = (short)(p0.y >> 16);
            ha[2] = (short)(p0.z >> 16); ha[3] = (short)(p0.w >> 16);
            ha[4] = (short)(p1.x >> 16); ha[5] = (short)(p1.y >> 16);
            ha[6] = (short)(p1.z >> 16); ha[7] = (short)(p1.w >> 16);
            accO = mfma16(ha, cb, accO);
        }
        #pragma unroll
        for (int i = 0; i < 4; ++i) {
            int row = t * BM + mo * 16 + lk * 4 + i;
            if (row < N_ROWS) out[(size_t)row * COUT + ocol] = accO[i] + bo;
        }
        __syncthreads();   // h fully consumed before next tile's staging write
    }
}

// ---------------- fallback: round-2 f32 kernel (proven; used only if ws too small) ----------------
__global__ __launch_bounds__(256) void fallback_f32(
    const float* __restrict__ x, const float* __restrict__ mask,
    const float* __restrict__ wzr, const float* __restrict__ whr,
    const float* __restrict__ bz, const float* __restrict__ bh,
    const float* __restrict__ wlinr, const float* __restrict__ blin,
    float* __restrict__ out)
{
    __shared__ float xm[32][CIN];
    const int tid = threadIdx.x;
    const int row0 = blockIdx.x * 32;
    #pragma unroll
    for (int it = 0; it < 8; ++it) {
        int idx = it * 256 + tid;
        int r = idx >> 6, c4 = idx & 63, row = row0 + r;
        float4 v = make_float4(0.f, 0.f, 0.f, 0.f);
        if (row < N_ROWS) {
            float4 a = reinterpret_cast<const float4*>(x    + (size_t)row * CIN)[c4];
            float4 m = reinterpret_cast<const float4*>(mask + (size_t)row * CIN)[c4];
            v = make_float4(a.x * m.x, a.y * m.y, a.z * m.z, a.w * m.w);
        }
        reinterpret_cast<float4*>(&xm[r][0])[c4] = v;
    }
    __syncthreads();
    const int j0 = (tid & 63) * 4, r0 = (tid >> 6) * 8;
    float accz[4][8], acch[4][8];
    #pragma unroll
    for (int c = 0; c < 4; ++c)
        #pragma unroll
        for (int r = 0; r < 8; ++r) { accz[c][r] = 0.f; acch[c][r] = 0.f; }
    for (int k = 0; k < CIN; k += 4) {
        float4 wz4[4], wh4[4];
        #pragma unroll
        for (int kk = 0; kk < 4; ++kk) {
            float4 a0 = *reinterpret_cast<const float4*>(&wzr[(k + kk) * 256 + j0]);
            float4 a1 = *reinterpret_cast<const float4*>(&wzr[131072 + (k + kk) * 256 + j0]);
            wz4[kk] = make_float4(a0.x + a1.x, a0.y + a1.y, a0.z + a1.z, a0.w + a1.w);
            float4 b0 = *reinterpret_cast<const float4*>(&whr[(k + kk) * 256 + j0]);
            float4 b1 = *reinterpret_cast<const float4*>(&whr[131072 + (k + kk) * 256 + j0]);
            wh4[kk] = make_float4(b0.x + b1.x, b0.y + b1.y, b0.z + b1.z, b0.w + b1.w);
        }
        #pragma unroll
        for (int r = 0; r < 8; ++r) {
            float4 xv = *reinterpret_cast<const float4*>(&xm[r0 + r][k]);
            float xk[4] = {xv.x, xv.y, xv.z, xv.w};
            float wzc[4][4] = {{wz4[0].x,wz4[0].y,wz4[0].z,wz4[0].w},{wz4[1].x,wz4[1].y,wz4[1].z,wz4[1].w},
                               {wz4[2].x,wz4[2].y,wz4[2].z,wz4[2].w},{wz4[3].x,wz4[3].y,wz4[3].z,wz4[3].w}};
            float whc[4][4] = {{wh4[0].x,wh4[0].y,wh4[0].z,wh4[0].w},{wh4[1].x,wh4[1].y,wh4[1].z,wh4[1].w},
                               {wh4[2].x,wh4[2].y,wh4[2].z,wh4[2].w},{wh4[3].x,wh4[3].y,wh4[3].z,wh4[3].w}};
            #pragma unroll
            for (int kk = 0; kk < 4; ++kk)
                #pragma unroll
                for (int c = 0; c < 4; ++c) {
                    accz[c][r] = fmaf(xk[kk], wzc[kk][c], accz[c][r]);
                    acch[c][r] = fmaf(xk[kk], whc[kk][c], acch[c][r]);
                }
        }
    }
    float bzj[4], bhj[4];
    #pragma unroll
    for (int c = 0; c < 4; ++c) { bzj[c] = bz[j0 + c]; bhj[c] = bh[j0 + c]; }
    __syncthreads();
    #pragma unroll
    for (int r = 0; r < 8; ++r) {
        float hc[4];
        #pragma unroll
        for (int c = 0; c < 4; ++c) {
            float z  = 1.f / (1.f + expf(-(accz[c][r] + bzj[c])));
            float ht = tanhf(acch[c][r] + bhj[c]);
            float H  = (1.f - z) * ht;
            hc[c] = (H > 0.f) ? H : expm1f(H);
        }
        *reinterpret_cast<float4*>(&xm[r0 + r][j0]) = make_float4(hc[0], hc[1], hc[2], hc[3]);
    }
    __syncthreads();
    const int o = tid & 63;
    float acc[8];
    #pragma unroll
    for (int r = 0; r < 8; ++r) acc[r] = 0.f;
    for (int k = 0; k < CIN; k += 4) {
        float4 wv4 = *reinterpret_cast<const float4*>(&wlinr[o * 256 + k]);
        #pragma unroll
        for (int r = 0; r < 8; ++r) {
            float4 hv = *reinterpret_cast<const float4*>(&xm[r0 + r][k]);
            acc[r] = fmaf(hv.x, wv4.x, acc[r]);
            acc[r] = fmaf(hv.y, wv4.y, acc[r]);
            acc[r] = fmaf(hv.z, wv4.z, acc[r]);
            acc[r] = fmaf(hv.w, wv4.w, acc[r]);
        }
    }
    float bo = blin[o];
    #pragma unroll
    for (int r = 0; r < 8; ++r) {
        int row = row0 + r0 + r;
        if (row < N_ROWS) out[(size_t)row * COUT + o] = acc[r] + bo;
    }
}

extern "C" void kernel_launch(void* const* d_in, const int* in_sizes, int n_in,
                              void* d_out, int out_size, void* d_ws, size_t ws_size,
                              hipStream_t stream)
{
    const float* x    = (const float*)d_in[0];
    // d_in[1] edge_index, d_in[2] edge_weight: unused (K=1 identity term only)
    const float* mask = (const float*)d_in[3];
    const float* wz   = (const float*)d_in[4];
    const float* bz   = (const float*)d_in[5];
    // d_in[6] w_r, d_in[7] b_r: dead (H=0 -> reset gate unused)
    const float* wh   = (const float*)d_in[8];
    const float* bh   = (const float*)d_in[9];
    const float* wlin = (const float*)d_in[10];
    const float* blin = (const float*)d_in[11];
    float* outf = (float*)d_out;

    const size_t ws_need = 288 * 1024;   // 288 frags x 1 KB
    if (ws_size >= ws_need) {
        unsigned short* wsf = (unsigned short*)d_ws;
        prep_frags<<<72, 256, 0, stream>>>(wz, wh, wlin, wsf);
        dcrnn_persist<<<GRID, 512, 0, stream>>>(
            x, mask, wsf, bz, bh, blin, outf);
    } else {
        fallback_f32<<<(N_ROWS + 31) / 32, 256, 0, stream>>>(
            x, mask, wz, wh, bz, bh, wlin, blin, outf);
    }
}

// Round 11
// 61.683 us; speedup vs baseline: 1.7243x; 1.4276x over previous
//
#include <hip/hip_runtime.h>
#include <hip/hip_bf16.h>

// DCRNN single-step, algebraically reduced (proven rounds 2-10):
//   xm = x * mask
//   Z  = sigmoid(xm @ WzE + bz),  WzE = w_z[0,0][:256] + w_z[1,0][:256]
//   Ht = tanh   (xm @ WhE + bh)
//   h  = elu((1 - Z) * Ht)         // H=0 -> Z*H drops; R/w_r/b_r dead; edges dead
//   out = h @ w_lin.T + b_lin      // f32 output
//
// Split-bf16 MFMA: x = xhi + xlo; W hi-only (absmax 0.015625 vs thr 0.0497, R7-R10).
// Round-11: weights stream through per-wave PRIVATE LDS double-buffers via
// __builtin_amdgcn_global_load_lds (zero VGPR cost, allocator-proof), synced by
// wave-local counted s_waitcnt vmcnt(2) only (no barrier in the K-loop).
// R6/R8/R9/R10 proved the allocator kills any register-carried weight pipeline.
// MFMA accumulation chains identical to R8 -> absmax exactly 0.015625.

typedef __attribute__((ext_vector_type(8))) short bf16x8;   // 8 bf16 = 4 VGPR
typedef __attribute__((ext_vector_type(4))) float f32x4;

constexpr int N_ROWS = 50000;
constexpr int CIN  = 256;
constexpr int COUT = 64;
constexpr int BM   = 32;

__device__ inline unsigned short f2bf(float f) {          // RNE f32 -> bf16 bits
    union { float f; unsigned u; } v; v.f = f;
    unsigned r = v.u + 0x7fffu + ((v.u >> 16) & 1u);
    return (unsigned short)(r >> 16);
}
__device__ inline float bf2f(unsigned short b) {
    union { unsigned u; float f; } v; v.u = ((unsigned)b) << 16;
    return v.f;
}
__device__ inline f32x4 mfma16(bf16x8 a, bf16x8 b, f32x4 c) {
    return __builtin_amdgcn_mfma_f32_16x16x32_bf16(a, b, c, 0, 0, 0);
}
__device__ __forceinline__ void gload16(const void* g, void* l) {
    // one fragment: 64 lanes x 16 B -> LDS at base + lane*16 (async, vmcnt-counted)
    __builtin_amdgcn_global_load_lds(
        (const __attribute__((address_space(1))) char*)g,
        (__attribute__((address_space(3))) char*)l, 16, 0, 0);
}

// ---------------- weight prep: B-fragment-ordered bf16 (hi only; proven R7-R10) ----------------
// Fragment f holds, for lane l, 8 bf16: B[k = kb*32 + (l>>4)*8 + j][n = nf*16 + (l&15)]
// gate frags f = (g*16 + nf)*8 + kb   g:0=Z,1=H   nf<16 kb<8   -> [0,256)
// out  frags f = 256 + nf*8 + kb      nf<4                     -> [256,288)
__global__ __launch_bounds__(256) void prep_frags(
    const float* __restrict__ wz, const float* __restrict__ wh,
    const float* __restrict__ wlin, unsigned short* __restrict__ ws)
{
    int t = blockIdx.x * 256 + threadIdx.x;
    int frag = t >> 6, lane = t & 63;
    if (frag >= 288) return;
    int g16 = lane & 15, kg = lane >> 4;
    unsigned short vals[8];
    if (frag < 256) {
        int kb = frag & 7, nf = (frag >> 3) & 15, g = frag >> 7;
        const float* wsrc = g ? wh : wz;
        int n = nf * 16 + g16;
        #pragma unroll
        for (int j = 0; j < 8; ++j) {
            int k = kb * 32 + kg * 8 + j;
            float v = wsrc[k * 256 + n] + wsrc[131072 + k * 256 + n];  // tap0 + tap1
            vals[j] = f2bf(v);
        }
    } else {
        int f = frag - 256;
        int kb = f & 7, nf = f >> 3;
        int n = nf * 16 + g16;                       // output column o
        #pragma unroll
        for (int j = 0; j < 8; ++j) {
            int k = kb * 32 + kg * 8 + j;
            vals[j] = f2bf(wlin[n * 256 + k]);       // B[k][o] = w_lin[o][k]
        }
    }
    unsigned short* dst = ws + (size_t)frag * 512 + lane * 8;
    #pragma unroll
    for (int j = 0; j < 8; ++j) dst[j] = vals[j];
}

// ---------------- fused MFMA kernel: async-LDS weight pipeline ----------------
__global__ __launch_bounds__(512)
__attribute__((amdgpu_waves_per_eu(4, 4)))
void dcrnn_async(
    const float* __restrict__ x, const float* __restrict__ mask,
    const unsigned short* __restrict__ wf,
    const float* __restrict__ bz, const float* __restrict__ bh,
    const float* __restrict__ blin, float* __restrict__ out)
{
    __shared__ char smem[65536];       // [0,32K): x hi/lo tile, later h; [32K,64K): 8 x 4KB wave dbufs
    char* AhiB = smem;                 // 16 KB, XOR-swizzled bf16 x_hi (32x256)
    char* AloB = smem + 16384;         // 16 KB, XOR-swizzled bf16 x_lo
    const int tid = threadIdx.x, lane = tid & 63, wv = tid >> 6;   // wv in [0,8)
    const int l16 = lane & 15, lk = lane >> 4;
    const int row0 = blockIdx.x * BM;
    const int nf0 = wv * 2;            // this wave's 2 nf slices (cols wv*32..+32)
    char* wbuf = smem + 32768 + wv * 4096;   // private dbuf: Z->half0 (+0), H->half1 (+2048)

    auto stage_gate = [&](int kb, int g) {   // 2 frags (nf0, nf0+1) of gate g at kb
        char* dst = wbuf + g * 2048;
        gload16(wf + (size_t)((g * 16 + nf0)     * 8 + kb) * 512 + lane * 8, dst);
        gload16(wf + (size_t)((g * 16 + nf0 + 1) * 8 + kb) * 512 + lane * 8, dst + 1024);
    };
    auto stage_out = [&](int v) {            // out frags kb=2v,2v+1 -> half (v&1)
        char* dst = wbuf + (v & 1) * 2048;
        gload16(wf + (size_t)(256 + (wv & 3) * 8 + 2 * v)     * 512 + lane * 8, dst);
        gload16(wf + (size_t)(256 + (wv & 3) * 8 + 2 * v + 1) * 512 + lane * 8, dst + 1024);
    };

    // ---- issue kb=0 weight stages first (in flight under x staging) ----
    stage_gate(0, 0);
    stage_gate(0, 1);

    // ---- bias constants ----
    float bzv[2], bhv[2];
    #pragma unroll
    for (int nfi = 0; nfi < 2; ++nfi) {
        int col = wv * 32 + nfi * 16 + l16;
        bzv[nfi] = bz[col]; bhv[nfi] = bh[col];
    }
    const int ocol = (wv & 3) * 16 + l16;
    const float bo = blin[ocol];
    const int mo = wv >> 2;

    // ---- stage xm = x*mask -> hi/lo bf16 in LDS (f32x4 loads, swizzled writes) ----
    #pragma unroll
    for (int it = 0; it < 4; ++it) {
        int s = it * 512 + tid, r = s >> 6, c4 = s & 63;
        int row = row0 + r;
        float4 xv = make_float4(0.f, 0.f, 0.f, 0.f), mv = xv;
        if (row < N_ROWS) {
            xv = reinterpret_cast<const float4*>(x    + (size_t)row * CIN)[c4];
            mv = reinterpret_cast<const float4*>(mask + (size_t)row * CIN)[c4];
        }
        float v0 = xv.x * mv.x, v1 = xv.y * mv.y, v2 = xv.z * mv.z, v3 = xv.w * mv.w;
        unsigned short h0 = f2bf(v0), h1 = f2bf(v1), h2 = f2bf(v2), h3 = f2bf(v3);
        unsigned short l0 = f2bf(v0 - bf2f(h0)), l1 = f2bf(v1 - bf2f(h1));
        unsigned short l2 = f2bf(v2 - bf2f(h2)), l3 = f2bf(v3 - bf2f(h3));
        int byte = ((r * CIN + c4 * 4) * 2) ^ ((r & 7) << 4);     // T2 swizzle, 16B slots
        *reinterpret_cast<ushort4*>(AhiB + byte) = make_ushort4(h0, h1, h2, h3);
        *reinterpret_cast<ushort4*>(AloB + byte) = make_ushort4(l0, l1, l2, l3);
    }
    __syncthreads();   // x tile visible; barrier drains vmcnt -> kb=0 stages arrived

    // ---- gate GEMMs: per-kb {Z unit, H unit}, weights via async LDS dbuf ----
    f32x4 accZ[2][2], accH[2][2];      // [nfi][m]
    #pragma unroll
    for (int nfi = 0; nfi < 2; ++nfi)
        #pragma unroll
        for (int m = 0; m < 2; ++m) {
            accZ[nfi][m] = (f32x4){0.f, 0.f, 0.f, 0.f};
            accH[nfi][m] = (f32x4){0.f, 0.f, 0.f, 0.f};
        }

    for (int kb = 0; kb < 8; ++kb) {
        bf16x8 ah[2], al[2];
        int koff = kb * 32 + lk * 8;
        #pragma unroll
        for (int m = 0; m < 2; ++m) {
            int row = m * 16 + l16;
            int byte = ((row * CIN + koff) * 2) ^ ((row & 7) << 4);
            ah[m] = *reinterpret_cast<const bf16x8*>(AhiB + byte);
            al[m] = *reinterpret_cast<const bf16x8*>(AloB + byte);
        }
        // --- Z unit (half0): steady-state outstanding = {Z(kb),H(kb)} = 4 loads ---
        if (kb >= 1) asm volatile("s_waitcnt vmcnt(2)" ::: "memory");   // Z(kb) arrived
        bf16x8 zb0 = *reinterpret_cast<const bf16x8*>(wbuf + lane * 16);
        bf16x8 zb1 = *reinterpret_cast<const bf16x8*>(wbuf + 1024 + lane * 16);
        asm volatile("s_waitcnt lgkmcnt(0)" ::: "memory");              // zb in VGPRs before overwrite
        if (kb < 7) stage_gate(kb + 1, 0); else stage_out(0);
        #pragma unroll
        for (int m = 0; m < 2; ++m) {
            accZ[0][m] = mfma16(ah[m], zb0, accZ[0][m]);
            accZ[0][m] = mfma16(al[m], zb0, accZ[0][m]);
            accZ[1][m] = mfma16(ah[m], zb1, accZ[1][m]);
            accZ[1][m] = mfma16(al[m], zb1, accZ[1][m]);
        }
        // --- H unit (half1) ---
        if (kb >= 1) asm volatile("s_waitcnt vmcnt(2)" ::: "memory");   // H(kb) arrived
        bf16x8 hb0 = *reinterpret_cast<const bf16x8*>(wbuf + 2048 + lane * 16);
        bf16x8 hb1 = *reinterpret_cast<const bf16x8*>(wbuf + 3072 + lane * 16);
        asm volatile("s_waitcnt lgkmcnt(0)" ::: "memory");
        if (kb < 7) stage_gate(kb + 1, 1); else stage_out(1);
        #pragma unroll
        for (int m = 0; m < 2; ++m) {
            accH[0][m] = mfma16(ah[m], hb0, accH[0][m]);
            accH[0][m] = mfma16(al[m], hb0, accH[0][m]);
            accH[1][m] = mfma16(ah[m], hb1, accH[1][m]);
            accH[1][m] = mfma16(al[m], hb1, accH[1][m]);
        }
    }
    __syncthreads();   // all waves done reading x before h overwrites smem

    // ---- nonlinearities + GRU blend; h -> LDS as (bf16 bits << 16) u32 ----
    #pragma unroll
    for (int nfi = 0; nfi < 2; ++nfi) {
        int col = wv * 32 + nfi * 16 + l16;
        #pragma unroll
        for (int m = 0; m < 2; ++m) {
            #pragma unroll
            for (int i = 0; i < 4; ++i) {
                float z  = 1.f / (1.f + __expf(-(accZ[nfi][m][i] + bzv[nfi])));
                float tt = __expf(2.f * (accH[nfi][m][i] + bhv[nfi]));
                float th = (tt - 1.f) / (tt + 1.f);
                float H  = (1.f - z) * th;
                float h  = (H > 0.f) ? H : (__expf(H) - 1.f);   // elu(alpha=1)
                int row = m * 16 + lk * 4 + i;                  // C/D: row=(lane>>4)*4+reg
                unsigned pk = ((unsigned)f2bf(h)) << 16;
                int byte = (row * 1024 + col * 4) ^ ((row & 7) << 4);
                *reinterpret_cast<unsigned*>(smem + byte) = pk;
            }
        }
    }
    __syncthreads();   // h visible; drains vmcnt -> out stages v0,v1 arrived

    // ---- out GEMM: wave wv -> rows [mo*16,+16), out-cols [(wv&3)*16,+16) ----
    f32x4 accO = (f32x4){0.f, 0.f, 0.f, 0.f};
    for (int v = 0; v < 4; ++v) {
        if (v == 2) asm volatile("s_waitcnt vmcnt(2)" ::: "memory");    // v2 arrived
        if (v == 3) asm volatile("s_waitcnt vmcnt(0)" ::: "memory");    // v3 arrived
        bf16x8 cb0 = *reinterpret_cast<const bf16x8*>(wbuf + (v & 1) * 2048 + lane * 16);
        bf16x8 cb1 = *reinterpret_cast<const bf16x8*>(wbuf + (v & 1) * 2048 + 1024 + lane * 16);
        asm volatile("s_waitcnt lgkmcnt(0)" ::: "memory");              // cb read before overwrite
        if (v < 2) stage_out(v + 2);
        #pragma unroll
        for (int j = 0; j < 2; ++j) {
            int kb = 2 * v + j;
            int row = mo * 16 + l16;
            int e0  = kb * 32 + lk * 8;
            int b0  = (row * 1024 + e0 * 4)      ^ ((row & 7) << 4);
            int b1  = (row * 1024 + e0 * 4 + 16) ^ ((row & 7) << 4);
            uint4 p0 = *reinterpret_cast<const uint4*>(smem + b0);
            uint4 p1 = *reinterpret_cast<const uint4*>(smem + b1);
            bf16x8 ha;
            ha[0] = (short)(p0.x >> 16); ha[1] = (short)(p0.y >> 16);
            ha[2] = (short)(p0.z >> 16); ha[3] = (short)(p0.w >> 16);
            ha[4] = (short)(p1.x >> 16); ha[5] = (short)(p1.y >> 16);
            ha[6] = (short)(p1.z >> 16); ha[7] = (short)(p1.w >> 16);
            accO = mfma16(ha, j ? cb1 : cb0, accO);
        }
    }
    #pragma unroll
    for (int i = 0; i < 4; ++i) {
        int row = row0 + mo * 16 + lk * 4 + i;
        if (row < N_ROWS) out[(size_t)row * COUT + ocol] = accO[i] + bo;
    }
}

// ---------------- fallback: round-2 f32 kernel (proven; used only if ws too small) ----------------
__global__ __launch_bounds__(256) void fallback_f32(
    const float* __restrict__ x, const float* __restrict__ mask,
    const float* __restrict__ wzr, const float* __restrict__ whr,
    const float* __restrict__ bz, const float* __restrict__ bh,
    const float* __restrict__ wlinr, const float* __restrict__ blin,
    float* __restrict__ out)
{
    __shared__ float xm[32][CIN];
    const int tid = threadIdx.x;
    const int row0 = blockIdx.x * 32;
    #pragma unroll
    for (int it = 0; it < 8; ++it) {
        int idx = it * 256 + tid;
        int r = idx >> 6, c4 = idx & 63, row = row0 + r;
        float4 v = make_float4(0.f, 0.f, 0.f, 0.f);
        if (row < N_ROWS) {
            float4 a = reinterpret_cast<const float4*>(x    + (size_t)row * CIN)[c4];
            float4 m = reinterpret_cast<const float4*>(mask + (size_t)row * CIN)[c4];
            v = make_float4(a.x * m.x, a.y * m.y, a.z * m.z, a.w * m.w);
        }
        reinterpret_cast<float4*>(&xm[r][0])[c4] = v;
    }
    __syncthreads();
    const int j0 = (tid & 63) * 4, r0 = (tid >> 6) * 8;
    float accz[4][8], acch[4][8];
    #pragma unroll
    for (int c = 0; c < 4; ++c)
        #pragma unroll
        for (int r = 0; r < 8; ++r) { accz[c][r] = 0.f; acch[c][r] = 0.f; }
    for (int k = 0; k < CIN; k += 4) {
        float4 wz4[4], wh4[4];
        #pragma unroll
        for (int kk = 0; kk < 4; ++kk) {
            float4 a0 = *reinterpret_cast<const float4*>(&wzr[(k + kk) * 256 + j0]);
            float4 a1 = *reinterpret_cast<const float4*>(&wzr[131072 + (k + kk) * 256 + j0]);
            wz4[kk] = make_float4(a0.x + a1.x, a0.y + a1.y, a0.z + a1.z, a0.w + a1.w);
            float4 b0 = *reinterpret_cast<const float4*>(&whr[(k + kk) * 256 + j0]);
            float4 b1 = *reinterpret_cast<const float4*>(&whr[131072 + (k + kk) * 256 + j0]);
            wh4[kk] = make_float4(b0.x + b1.x, b0.y + b1.y, b0.z + b1.z, b0.w + b1.w);
        }
        #pragma unroll
        for (int r = 0; r < 8; ++r) {
            float4 xv = *reinterpret_cast<const float4*>(&xm[r0 + r][k]);
            float xk[4] = {xv.x, xv.y, xv.z, xv.w};
            float wzc[4][4] = {{wz4[0].x,wz4[0].y,wz4[0].z,wz4[0].w},{wz4[1].x,wz4[1].y,wz4[1].z,wz4[1].w},
                               {wz4[2].x,wz4[2].y,wz4[2].z,wz4[2].w},{wz4[3].x,wz4[3].y,wz4[3].z,wz4[3].w}};
            float whc[4][4] = {{wh4[0].x,wh4[0].y,wh4[0].z,wh4[0].w},{wh4[1].x,wh4[1].y,wh4[1].z,wh4[1].w},
                               {wh4[2].x,wh4[2].y,wh4[2].z,wh4[2].w},{wh4[3].x,wh4[3].y,wh4[3].z,wh4[3].w}};
            #pragma unroll
            for (int kk = 0; kk < 4; ++kk)
                #pragma unroll
                for (int c = 0; c < 4; ++c) {
                    accz[c][r] = fmaf(xk[kk], wzc[kk][c], accz[c][r]);
                    acch[c][r] = fmaf(xk[kk], whc[kk][c], acch[c][r]);
                }
        }
    }
    float bzj[4], bhj[4];
    #pragma unroll
    for (int c = 0; c < 4; ++c) { bzj[c] = bz[j0 + c]; bhj[c] = bh[j0 + c]; }
    __syncthreads();
    #pragma unroll
    for (int r = 0; r < 8; ++r) {
        float hc[4];
        #pragma unroll
        for (int c = 0; c < 4; ++c) {
            float z  = 1.f / (1.f + expf(-(accz[c][r] + bzj[c])));
            float ht = tanhf(acch[c][r] + bhj[c]);
            float H  = (1.f - z) * ht;
            hc[c] = (H > 0.f) ? H : expm1f(H);
        }
        *reinterpret_cast<float4*>(&xm[r0 + r][j0]) = make_float4(hc[0], hc[1], hc[2], hc[3]);
    }
    __syncthreads();
    const int o = tid & 63;
    float acc[8];
    #pragma unroll
    for (int r = 0; r < 8; ++r) acc[r] = 0.f;
    for (int k = 0; k < CIN; k += 4) {
        float4 wv4 = *reinterpret_cast<const float4*>(&wlinr[o * 256 + k]);
        #pragma unroll
        for (int r = 0; r < 8; ++r) {
            float4 hv = *reinterpret_cast<const float4*>(&xm[r0 + r][k]);
            acc[r] = fmaf(hv.x, wv4.x, acc[r]);
            acc[r] = fmaf(hv.y, wv4.y, acc[r]);
            acc[r] = fmaf(hv.z, wv4.z, acc[r]);
            acc[r] = fmaf(hv.w, wv4.w, acc[r]);
        }
    }
    float bo = blin[o];
    #pragma unroll
    for (int r = 0; r < 8; ++r) {
        int row = row0 + r0 + r;
        if (row < N_ROWS) out[(size_t)row * COUT + o] = acc[r] + bo;
    }
}

extern "C" void kernel_launch(void* const* d_in, const int* in_sizes, int n_in,
                              void* d_out, int out_size, void* d_ws, size_t ws_size,
                              hipStream_t stream)
{
    const float* x    = (const float*)d_in[0];
    // d_in[1] edge_index, d_in[2] edge_weight: unused (K=1 identity term only)
    const float* mask = (const float*)d_in[3];
    const float* wz   = (const float*)d_in[4];
    const float* bz   = (const float*)d_in[5];
    // d_in[6] w_r, d_in[7] b_r: dead (H=0 -> reset gate unused)
    const float* wh   = (const float*)d_in[8];
    const float* bh   = (const float*)d_in[9];
    const float* wlin = (const float*)d_in[10];
    const float* blin = (const float*)d_in[11];
    float* outf = (float*)d_out;

    const size_t ws_need = 288 * 1024;   // 288 frags x 1 KB
    if (ws_size >= ws_need) {
        unsigned short* wsf = (unsigned short*)d_ws;
        prep_frags<<<72, 256, 0, stream>>>(wz, wh, wlin, wsf);
        dcrnn_async<<<(N_ROWS + BM - 1) / BM, 512, 0, stream>>>(
            x, mask, wsf, bz, bh, blin, outf);
    } else {
        fallback_f32<<<(N_ROWS + 31) / 32, 256, 0, stream>>>(
            x, mask, wz, wh, bz, bh, wlin, blin, outf);
    }
}

// Round 12
// 56.967 us; speedup vs baseline: 1.8670x; 1.0828x over previous
//
#include <hip/hip_runtime.h>
#include <hip/hip_bf16.h>

// DCRNN single-step, algebraically reduced (proven rounds 2-11):
//   xm = x * mask
//   Z  = sigmoid(xm @ WzE + bz),  WzE = w_z[0,0][:256] + w_z[1,0][:256]
//   Ht = tanh   (xm @ WhE + bh)
//   h  = elu((1 - Z) * Ht)         // H=0 -> Z*H drops; R/w_r/b_r dead; edges dead
//   out = h @ w_lin.T + b_lin      // f32 output
//
// Precision: single-bf16 MFMA both sides (x-hi * W-hi). W-lo dropped in R7
// (0.0078->0.0156); x-lo dropped this round (same-magnitude error channel,
// est total ~0.023-0.031 vs thr 0.0497).
// Round-12: LDS 64->48 KB (3 blocks/CU, 24 waves), staging VALU -40%, gate
// MFMAs halved; weights still stream via per-wave private LDS dbufs with
// counted wave-local vmcnt (R11-proven, allocator-proof); out-weights via
// direct global->VGPR depth-1 prefetch (R7/R8-proven).

typedef __attribute__((ext_vector_type(8))) short bf16x8;   // 8 bf16 = 4 VGPR
typedef __attribute__((ext_vector_type(4))) float f32x4;

constexpr int N_ROWS = 50000;
constexpr int CIN  = 256;
constexpr int COUT = 64;
constexpr int BM   = 32;

__device__ inline unsigned short f2bf(float f) {          // RNE f32 -> bf16 bits
    union { float f; unsigned u; } v; v.f = f;
    unsigned r = v.u + 0x7fffu + ((v.u >> 16) & 1u);
    return (unsigned short)(r >> 16);
}
__device__ inline f32x4 mfma16(bf16x8 a, bf16x8 b, f32x4 c) {
    return __builtin_amdgcn_mfma_f32_16x16x32_bf16(a, b, c, 0, 0, 0);
}
__device__ __forceinline__ void gload16(const void* g, void* l) {
    // one fragment: 64 lanes x 16 B -> LDS at base + lane*16 (async, vmcnt-counted)
    __builtin_amdgcn_global_load_lds(
        (const __attribute__((address_space(1))) char*)g,
        (__attribute__((address_space(3))) char*)l, 16, 0, 0);
}

// ---------------- weight prep: B-fragment-ordered bf16 (hi only; proven R7-R11) ----------------
// Fragment f holds, for lane l, 8 bf16: B[k = kb*32 + (l>>4)*8 + j][n = nf*16 + (l&15)]
// gate frags f = (g*16 + nf)*8 + kb   g:0=Z,1=H   nf<16 kb<8   -> [0,256)
// out  frags f = 256 + nf*8 + kb      nf<4                     -> [256,288)
__global__ __launch_bounds__(256) void prep_frags(
    const float* __restrict__ wz, const float* __restrict__ wh,
    const float* __restrict__ wlin, unsigned short* __restrict__ ws)
{
    int t = blockIdx.x * 256 + threadIdx.x;
    int frag = t >> 6, lane = t & 63;
    if (frag >= 288) return;
    int g16 = lane & 15, kg = lane >> 4;
    unsigned short vals[8];
    if (frag < 256) {
        int kb = frag & 7, nf = (frag >> 3) & 15, g = frag >> 7;
        const float* wsrc = g ? wh : wz;
        int n = nf * 16 + g16;
        #pragma unroll
        for (int j = 0; j < 8; ++j) {
            int k = kb * 32 + kg * 8 + j;
            float v = wsrc[k * 256 + n] + wsrc[131072 + k * 256 + n];  // tap0 + tap1
            vals[j] = f2bf(v);
        }
    } else {
        int f = frag - 256;
        int kb = f & 7, nf = f >> 3;
        int n = nf * 16 + g16;                       // output column o
        #pragma unroll
        for (int j = 0; j < 8; ++j) {
            int k = kb * 32 + kg * 8 + j;
            vals[j] = f2bf(wlin[n * 256 + k]);       // B[k][o] = w_lin[o][k]
        }
    }
    unsigned short* dst = ws + (size_t)frag * 512 + lane * 8;
    #pragma unroll
    for (int j = 0; j < 8; ++j) dst[j] = vals[j];
}

__device__ inline bf16x8 ldfrag(const unsigned short* wf, int frag, int lane) {
    return *reinterpret_cast<const bf16x8*>(wf + (size_t)frag * 512 + lane * 8);
}

// ---------------- fused MFMA kernel: 48 KB LDS, async weight pipeline ----------------
__global__ __launch_bounds__(512)
__attribute__((amdgpu_waves_per_eu(6, 6)))
void dcrnn_async(
    const float* __restrict__ x, const float* __restrict__ mask,
    const unsigned short* __restrict__ wf,
    const float* __restrict__ bz, const float* __restrict__ bh,
    const float* __restrict__ blin, float* __restrict__ out)
{
    __shared__ char smem[49152];       // [0,16K): x_hi staging; [16K,48K): 8 x 4KB wave dbufs
                                       // after gate barrier: h overlays [0,32K) (all dead then)
    char* AhiB = smem;                 // 16 KB, XOR-swizzled bf16 x_hi (32x256)
    const int tid = threadIdx.x, lane = tid & 63, wv = tid >> 6;   // wv in [0,8)
    const int l16 = lane & 15, lk = lane >> 4;
    const int row0 = blockIdx.x * BM;
    const int nf0 = wv * 2;            // this wave's 2 nf slices (cols wv*32..+32)
    char* wbuf = smem + 16384 + wv * 4096;   // private dbuf: Z->half0 (+0), H->half1 (+2048)

    auto stage_gate = [&](int kb, int g) {   // 2 frags (nf0, nf0+1) of gate g at kb
        char* dst = wbuf + g * 2048;
        gload16(wf + (size_t)((g * 16 + nf0)     * 8 + kb) * 512 + lane * 8, dst);
        gload16(wf + (size_t)((g * 16 + nf0 + 1) * 8 + kb) * 512 + lane * 8, dst + 1024);
    };

    // ---- issue kb=0 weight stages first (in flight under x staging) ----
    stage_gate(0, 0);
    stage_gate(0, 1);

    // ---- bias constants ----
    float bzv[2], bhv[2];
    #pragma unroll
    for (int nfi = 0; nfi < 2; ++nfi) {
        int col = wv * 32 + nfi * 16 + l16;
        bzv[nfi] = bz[col]; bhv[nfi] = bh[col];
    }
    const int ocol = (wv & 3) * 16 + l16;
    const float bo = blin[ocol];
    const int mo = wv >> 2;

    // ---- stage xm = x*mask -> bf16(hi) in LDS (f32x4 loads, swizzled 8B writes) ----
    #pragma unroll
    for (int it = 0; it < 4; ++it) {
        int s = it * 512 + tid, r = s >> 6, c4 = s & 63;
        int row = row0 + r;
        float4 xv = make_float4(0.f, 0.f, 0.f, 0.f), mv = xv;
        if (row < N_ROWS) {
            xv = reinterpret_cast<const float4*>(x    + (size_t)row * CIN)[c4];
            mv = reinterpret_cast<const float4*>(mask + (size_t)row * CIN)[c4];
        }
        unsigned short h0 = f2bf(xv.x * mv.x), h1 = f2bf(xv.y * mv.y);
        unsigned short h2 = f2bf(xv.z * mv.z), h3 = f2bf(xv.w * mv.w);
        int byte = ((r * CIN + c4 * 4) * 2) ^ ((r & 7) << 4);     // T2 swizzle (same as R11)
        *reinterpret_cast<ushort4*>(AhiB + byte) = make_ushort4(h0, h1, h2, h3);
    }
    __syncthreads();   // x tile visible; barrier drains vmcnt -> kb=0 stages arrived

    // ---- gate GEMMs: per-kb {Z unit, H unit}, weights via async LDS dbuf ----
    f32x4 accZ[2][2], accH[2][2];      // [nfi][m]
    #pragma unroll
    for (int nfi = 0; nfi < 2; ++nfi)
        #pragma unroll
        for (int m = 0; m < 2; ++m) {
            accZ[nfi][m] = (f32x4){0.f, 0.f, 0.f, 0.f};
            accH[nfi][m] = (f32x4){0.f, 0.f, 0.f, 0.f};
        }

    for (int kb = 0; kb < 8; ++kb) {
        bf16x8 ah[2];
        int koff = kb * 32 + lk * 8;
        #pragma unroll
        for (int m = 0; m < 2; ++m) {
            int row = m * 16 + l16;
            int byte = ((row * CIN + koff) * 2) ^ ((row & 7) << 4);
            ah[m] = *reinterpret_cast<const bf16x8*>(AhiB + byte);
        }
        // --- Z unit (half0): steady-state outstanding = {Z(kb),H(kb)} = 4 loads ---
        if (kb >= 1) asm volatile("s_waitcnt vmcnt(2)" ::: "memory");   // Z(kb) arrived
        bf16x8 zb0 = *reinterpret_cast<const bf16x8*>(wbuf + lane * 16);
        bf16x8 zb1 = *reinterpret_cast<const bf16x8*>(wbuf + 1024 + lane * 16);
        asm volatile("s_waitcnt lgkmcnt(0)" ::: "memory");              // zb in VGPRs before overwrite
        if (kb < 7) stage_gate(kb + 1, 0);
        #pragma unroll
        for (int m = 0; m < 2; ++m) {
            accZ[0][m] = mfma16(ah[m], zb0, accZ[0][m]);
            accZ[1][m] = mfma16(ah[m], zb1, accZ[1][m]);
        }
        // --- H unit (half1) ---
        if (kb == 7)      asm volatile("s_waitcnt vmcnt(0)" ::: "memory");  // no trailing stage
        else if (kb >= 1) asm volatile("s_waitcnt vmcnt(2)" ::: "memory");  // H(kb) arrived
        bf16x8 hb0 = *reinterpret_cast<const bf16x8*>(wbuf + 2048 + lane * 16);
        bf16x8 hb1 = *reinterpret_cast<const bf16x8*>(wbuf + 3072 + lane * 16);
        asm volatile("s_waitcnt lgkmcnt(0)" ::: "memory");
        if (kb < 7) stage_gate(kb + 1, 1);
        #pragma unroll
        for (int m = 0; m < 2; ++m) {
            accH[0][m] = mfma16(ah[m], hb0, accH[0][m]);
            accH[1][m] = mfma16(ah[m], hb1, accH[1][m]);
        }
    }
    // issue first out-weight load (global->VGPR) before the barrier; lands under epilogue
    bf16x8 cb = ldfrag(wf, 256 + (wv & 3) * 8, lane);
    __syncthreads();   // all waves done reading x/dbufs before h overwrites smem[0,32K)

    // ---- nonlinearities + GRU blend; h -> LDS as (bf16 bits << 16) u32 (word stores) ----
    #pragma unroll
    for (int nfi = 0; nfi < 2; ++nfi) {
        int col = wv * 32 + nfi * 16 + l16;
        #pragma unroll
        for (int m = 0; m < 2; ++m) {
            #pragma unroll
            for (int i = 0; i < 4; ++i) {
                float z  = 1.f / (1.f + __expf(-(accZ[nfi][m][i] + bzv[nfi])));
                float tt = __expf(2.f * (accH[nfi][m][i] + bhv[nfi]));
                float th = (tt - 1.f) / (tt + 1.f);
                float H  = (1.f - z) * th;
                float h  = (H > 0.f) ? H : (__expf(H) - 1.f);   // elu(alpha=1)
                int row = m * 16 + lk * 4 + i;                  // C/D: row=(lane>>4)*4+reg
                unsigned pk = ((unsigned)f2bf(h)) << 16;
                int byte = (row * 1024 + col * 4) ^ ((row & 7) << 4);  // u32, row stride 1 KB
                *reinterpret_cast<unsigned*>(smem + byte) = pk;
            }
        }
    }
    __syncthreads();   // h visible to all waves

    // ---- out GEMM: wave wv -> rows [mo*16,+16), out-cols [(wv&3)*16,+16) ----
    f32x4 accO = (f32x4){0.f, 0.f, 0.f, 0.f};
    for (int kb = 0; kb < 8; ++kb) {
        int nk = kb < 7 ? kb + 1 : 7;
        bf16x8 nb = ldfrag(wf, 256 + (wv & 3) * 8 + nk, lane);    // depth-1 prefetch
        int row = mo * 16 + l16;
        int e0  = kb * 32 + lk * 8;
        int b0  = (row * 1024 + e0 * 4)      ^ ((row & 7) << 4);
        int b1  = (row * 1024 + e0 * 4 + 16) ^ ((row & 7) << 4);
        uint4 p0 = *reinterpret_cast<const uint4*>(smem + b0);
        uint4 p1 = *reinterpret_cast<const uint4*>(smem + b1);
        bf16x8 ha;
        ha[0] = (short)(p0.x >> 16); ha[1] = (short)(p0.y >> 16);
        ha[2] = (short)(p0.z >> 16); ha[3] = (short)(p0.w >> 16);
        ha[4] = (short)(p1.x >> 16); ha[5] = (short)(p1.y >> 16);
        ha[6] = (short)(p1.z >> 16); ha[7] = (short)(p1.w >> 16);
        accO = mfma16(ha, cb, accO);
        cb = nb;
    }
    #pragma unroll
    for (int i = 0; i < 4; ++i) {
        int row = row0 + mo * 16 + lk * 4 + i;
        if (row < N_ROWS) out[(size_t)row * COUT + ocol] = accO[i] + bo;
    }
}

// ---------------- fallback: round-2 f32 kernel (proven; used only if ws too small) ----------------
__global__ __launch_bounds__(256) void fallback_f32(
    const float* __restrict__ x, const float* __restrict__ mask,
    const float* __restrict__ wzr, const float* __restrict__ whr,
    const float* __restrict__ bz, const float* __restrict__ bh,
    const float* __restrict__ wlinr, const float* __restrict__ blin,
    float* __restrict__ out)
{
    __shared__ float xm[32][CIN];
    const int tid = threadIdx.x;
    const int row0 = blockIdx.x * 32;
    #pragma unroll
    for (int it = 0; it < 8; ++it) {
        int idx = it * 256 + tid;
        int r = idx >> 6, c4 = idx & 63, row = row0 + r;
        float4 v = make_float4(0.f, 0.f, 0.f, 0.f);
        if (row < N_ROWS) {
            float4 a = reinterpret_cast<const float4*>(x    + (size_t)row * CIN)[c4];
            float4 m = reinterpret_cast<const float4*>(mask + (size_t)row * CIN)[c4];
            v = make_float4(a.x * m.x, a.y * m.y, a.z * m.z, a.w * m.w);
        }
        reinterpret_cast<float4*>(&xm[r][0])[c4] = v;
    }
    __syncthreads();
    const int j0 = (tid & 63) * 4, r0 = (tid >> 6) * 8;
    float accz[4][8], acch[4][8];
    #pragma unroll
    for (int c = 0; c < 4; ++c)
        #pragma unroll
        for (int r = 0; r < 8; ++r) { accz[c][r] = 0.f; acch[c][r] = 0.f; }
    for (int k = 0; k < CIN; k += 4) {
        float4 wz4[4], wh4[4];
        #pragma unroll
        for (int kk = 0; kk < 4; ++kk) {
            float4 a0 = *reinterpret_cast<const float4*>(&wzr[(k + kk) * 256 + j0]);
            float4 a1 = *reinterpret_cast<const float4*>(&wzr[131072 + (k + kk) * 256 + j0]);
            wz4[kk] = make_float4(a0.x + a1.x, a0.y + a1.y, a0.z + a1.z, a0.w + a1.w);
            float4 b0 = *reinterpret_cast<const float4*>(&whr[(k + kk) * 256 + j0]);
            float4 b1 = *reinterpret_cast<const float4*>(&whr[131072 + (k + kk) * 256 + j0]);
            wh4[kk] = make_float4(b0.x + b1.x, b0.y + b1.y, b0.z + b1.z, b0.w + b1.w);
        }
        #pragma unroll
        for (int r = 0; r < 8; ++r) {
            float4 xv = *reinterpret_cast<const float4*>(&xm[r0 + r][k]);
            float xk[4] = {xv.x, xv.y, xv.z, xv.w};
            float wzc[4][4] = {{wz4[0].x,wz4[0].y,wz4[0].z,wz4[0].w},{wz4[1].x,wz4[1].y,wz4[1].z,wz4[1].w},
                               {wz4[2].x,wz4[2].y,wz4[2].z,wz4[2].w},{wz4[3].x,wz4[3].y,wz4[3].z,wz4[3].w}};
            float whc[4][4] = {{wh4[0].x,wh4[0].y,wh4[0].z,wh4[0].w},{wh4[1].x,wh4[1].y,wh4[1].z,wh4[1].w},
                               {wh4[2].x,wh4[2].y,wh4[2].z,wh4[2].w},{wh4[3].x,wh4[3].y,wh4[3].z,wh4[3].w}};
            #pragma unroll
            for (int kk = 0; kk < 4; ++kk)
                #pragma unroll
                for (int c = 0; c < 4; ++c) {
                    accz[c][r] = fmaf(xk[kk], wzc[kk][c], accz[c][r]);
                    acch[c][r] = fmaf(xk[kk], whc[kk][c], acch[c][r]);
                }
        }
    }
    float bzj[4], bhj[4];
    #pragma unroll
    for (int c = 0; c < 4; ++c) { bzj[c] = bz[j0 + c]; bhj[c] = bh[j0 + c]; }
    __syncthreads();
    #pragma unroll
    for (int r = 0; r < 8; ++r) {
        float hc[4];
        #pragma unroll
        for (int c = 0; c < 4; ++c) {
            float z  = 1.f / (1.f + expf(-(accz[c][r] + bzj[c])));
            float ht = tanhf(acch[c][r] + bhj[c]);
            float H  = (1.f - z) * ht;
            hc[c] = (H > 0.f) ? H : expm1f(H);
        }
        *reinterpret_cast<float4*>(&xm[r0 + r][j0]) = make_float4(hc[0], hc[1], hc[2], hc[3]);
    }
    __syncthreads();
    const int o = tid & 63;
    float acc[8];
    #pragma unroll
    for (int r = 0; r < 8; ++r) acc[r] = 0.f;
    for (int k = 0; k < CIN; k += 4) {
        float4 wv4 = *reinterpret_cast<const float4*>(&wlinr[o * 256 + k]);
        #pragma unroll
        for (int r = 0; r < 8; ++r) {
            float4 hv = *reinterpret_cast<const float4*>(&xm[r0 + r][k]);
            acc[r] = fmaf(hv.x, wv4.x, acc[r]);
            acc[r] = fmaf(hv.y, wv4.y, acc[r]);
            acc[r] = fmaf(hv.z, wv4.z, acc[r]);
            acc[r] = fmaf(hv.w, wv4.w, acc[r]);
        }
    }
    float bo = blin[o];
    #pragma unroll
    for (int r = 0; r < 8; ++r) {
        int row = row0 + r0 + r;
        if (row < N_ROWS) out[(size_t)row * COUT + o] = acc[r] + bo;
    }
}

extern "C" void kernel_launch(void* const* d_in, const int* in_sizes, int n_in,
                              void* d_out, int out_size, void* d_ws, size_t ws_size,
                              hipStream_t stream)
{
    const float* x    = (const float*)d_in[0];
    // d_in[1] edge_index, d_in[2] edge_weight: unused (K=1 identity term only)
    const float* mask = (const float*)d_in[3];
    const float* wz   = (const float*)d_in[4];
    const float* bz   = (const float*)d_in[5];
    // d_in[6] w_r, d_in[7] b_r: dead (H=0 -> reset gate unused)
    const float* wh   = (const float*)d_in[8];
    const float* bh   = (const float*)d_in[9];
    const float* wlin = (const float*)d_in[10];
    const float* blin = (const float*)d_in[11];
    float* outf = (float*)d_out;

    const size_t ws_need = 288 * 1024;   // 288 frags x 1 KB
    if (ws_size >= ws_need) {
        unsigned short* wsf = (unsigned short*)d_ws;
        prep_frags<<<72, 256, 0, stream>>>(wz, wh, wlin, wsf);
        dcrnn_async<<<(N_ROWS + BM - 1) / BM, 512, 0, stream>>>(
            x, mask, wsf, bz, bh, blin, outf);
    } else {
        fallback_f32<<<(N_ROWS + 31) / 32, 256, 0, stream>>>(
            x, mask, wz, wh, bz, bh, wlin, blin, outf);
    }
}

// Round 13
// 56.187 us; speedup vs baseline: 1.8929x; 1.0139x over previous
//
#include <hip/hip_runtime.h>
#include <hip/hip_bf16.h>

// DCRNN single-step, algebraically reduced (proven rounds 2-12):
//   xm = x * mask
//   Z  = sigmoid(xm @ WzE + bz),  WzE = w_z[0,0][:256] + w_z[1,0][:256]
//   Ht = tanh   (xm @ WhE + bh)
//   h  = elu((1 - Z) * Ht)         // H=0 -> Z*H drops; R/w_r/b_r dead; edges dead
//   out = h @ w_lin.T + b_lin      // f32 output
//
// Precision: single-bf16 MFMA both sides (x-hi * W-hi), absmax 0.015625 (R12).
// Round-13: BM 32->64 at same 512-thread/8-wave skeleton — 8 MFMAs per vmcnt
// wait unit (2x latency cover), per-block weight stream amortized over 2x rows
// (L2 weight traffic halved). LDS 64 KB (x 32K + dbufs 32K; h overlays all
// after gate barrier). waves_per_eu(4,4) pins the 128-VGPR tier (acc=64).
// Per-element MFMA chains order-identical to R12 -> absmax exactly 0.015625.

typedef __attribute__((ext_vector_type(8))) short bf16x8;   // 8 bf16 = 4 VGPR
typedef __attribute__((ext_vector_type(4))) float f32x4;

constexpr int N_ROWS = 50000;
constexpr int CIN  = 256;
constexpr int COUT = 64;
constexpr int BM   = 64;

__device__ inline unsigned short f2bf(float f) {          // RNE f32 -> bf16 bits
    union { float f; unsigned u; } v; v.f = f;
    unsigned r = v.u + 0x7fffu + ((v.u >> 16) & 1u);
    return (unsigned short)(r >> 16);
}
__device__ inline f32x4 mfma16(bf16x8 a, bf16x8 b, f32x4 c) {
    return __builtin_amdgcn_mfma_f32_16x16x32_bf16(a, b, c, 0, 0, 0);
}
__device__ __forceinline__ void gload16(const void* g, void* l) {
    // one fragment: 64 lanes x 16 B -> LDS at base + lane*16 (async, vmcnt-counted)
    __builtin_amdgcn_global_load_lds(
        (const __attribute__((address_space(1))) char*)g,
        (__attribute__((address_space(3))) char*)l, 16, 0, 0);
}

// ---------------- weight prep: B-fragment-ordered bf16 (hi only; proven R7-R12) ----------------
// Fragment f holds, for lane l, 8 bf16: B[k = kb*32 + (l>>4)*8 + j][n = nf*16 + (l&15)]
// gate frags f = (g*16 + nf)*8 + kb   g:0=Z,1=H   nf<16 kb<8   -> [0,256)
// out  frags f = 256 + nf*8 + kb      nf<4                     -> [256,288)
__global__ __launch_bounds__(256) void prep_frags(
    const float* __restrict__ wz, const float* __restrict__ wh,
    const float* __restrict__ wlin, unsigned short* __restrict__ ws)
{
    int t = blockIdx.x * 256 + threadIdx.x;
    int frag = t >> 6, lane = t & 63;
    if (frag >= 288) return;
    int g16 = lane & 15, kg = lane >> 4;
    unsigned short vals[8];
    if (frag < 256) {
        int kb = frag & 7, nf = (frag >> 3) & 15, g = frag >> 7;
        const float* wsrc = g ? wh : wz;
        int n = nf * 16 + g16;
        #pragma unroll
        for (int j = 0; j < 8; ++j) {
            int k = kb * 32 + kg * 8 + j;
            float v = wsrc[k * 256 + n] + wsrc[131072 + k * 256 + n];  // tap0 + tap1
            vals[j] = f2bf(v);
        }
    } else {
        int f = frag - 256;
        int kb = f & 7, nf = f >> 3;
        int n = nf * 16 + g16;                       // output column o
        #pragma unroll
        for (int j = 0; j < 8; ++j) {
            int k = kb * 32 + kg * 8 + j;
            vals[j] = f2bf(wlin[n * 256 + k]);       // B[k][o] = w_lin[o][k]
        }
    }
    unsigned short* dst = ws + (size_t)frag * 512 + lane * 8;
    #pragma unroll
    for (int j = 0; j < 8; ++j) dst[j] = vals[j];
}

__device__ inline bf16x8 ldfrag(const unsigned short* wf, int frag, int lane) {
    return *reinterpret_cast<const bf16x8*>(wf + (size_t)frag * 512 + lane * 8);
}

// ---------------- fused MFMA kernel: BM=64, async weight pipeline ----------------
__global__ __launch_bounds__(512)
__attribute__((amdgpu_waves_per_eu(4, 4)))
void dcrnn_async(
    const float* __restrict__ x, const float* __restrict__ mask,
    const unsigned short* __restrict__ wf,
    const float* __restrict__ bz, const float* __restrict__ bh,
    const float* __restrict__ blin, float* __restrict__ out)
{
    __shared__ char smem[65536];       // [0,32K): x_hi (64x256 bf16, swz); [32K,64K): 8 x 4KB dbufs
                                       // after gate barrier: h (u32, 64 rows x 1KB) overlays all 64K
    char* AhiB = smem;
    const int tid = threadIdx.x, lane = tid & 63, wv = tid >> 6;   // wv in [0,8)
    const int l16 = lane & 15, lk = lane >> 4;
    const int row0 = blockIdx.x * BM;
    const int nf0 = wv * 2;            // this wave's 2 nf slices (cols wv*32..+32)
    char* wbuf = smem + 32768 + wv * 4096;   // private dbuf: Z->half0 (+0), H->half1 (+2048)

    auto stage_gate = [&](int kb, int g) {   // 2 frags (nf0, nf0+1) of gate g at kb
        char* dst = wbuf + g * 2048;
        gload16(wf + (size_t)((g * 16 + nf0)     * 8 + kb) * 512 + lane * 8, dst);
        gload16(wf + (size_t)((g * 16 + nf0 + 1) * 8 + kb) * 512 + lane * 8, dst + 1024);
    };

    // ---- issue kb=0 weight stages first (in flight under x staging) ----
    stage_gate(0, 0);
    stage_gate(0, 1);

    // ---- bias constants ----
    float bzv[2], bhv[2];
    #pragma unroll
    for (int nfi = 0; nfi < 2; ++nfi) {
        int col = wv * 32 + nfi * 16 + l16;
        bzv[nfi] = bz[col]; bhv[nfi] = bh[col];
    }
    const int ocol = (wv & 3) * 16 + l16;
    const float bo = blin[ocol];
    const int mo = wv >> 2;            // out-GEMM row half: rows [mo*32, mo*32+32)

    // ---- stage xm = x*mask -> bf16(hi) in LDS (f32x4 loads, swizzled 8B writes) ----
    #pragma unroll
    for (int it = 0; it < 8; ++it) {
        int s = it * 512 + tid, r = s >> 6, c4 = s & 63;   // r in [0,64)
        int row = row0 + r;
        float4 xv = make_float4(0.f, 0.f, 0.f, 0.f), mv = xv;
        if (row < N_ROWS) {
            xv = reinterpret_cast<const float4*>(x    + (size_t)row * CIN)[c4];
            mv = reinterpret_cast<const float4*>(mask + (size_t)row * CIN)[c4];
        }
        unsigned short h0 = f2bf(xv.x * mv.x), h1 = f2bf(xv.y * mv.y);
        unsigned short h2 = f2bf(xv.z * mv.z), h3 = f2bf(xv.w * mv.w);
        int byte = ((r * CIN + c4 * 4) * 2) ^ ((r & 7) << 4);     // T2 swizzle (proven)
        *reinterpret_cast<ushort4*>(AhiB + byte) = make_ushort4(h0, h1, h2, h3);
    }
    __syncthreads();   // x tile visible; barrier drains vmcnt -> kb=0 stages arrived

    // ---- gate GEMMs: 4 m-frags x 2 nf, weights via async LDS dbuf ----
    f32x4 accZ[2][4], accH[2][4];      // [nfi][m]
    #pragma unroll
    for (int nfi = 0; nfi < 2; ++nfi)
        #pragma unroll
        for (int m = 0; m < 4; ++m) {
            accZ[nfi][m] = (f32x4){0.f, 0.f, 0.f, 0.f};
            accH[nfi][m] = (f32x4){0.f, 0.f, 0.f, 0.f};
        }

    for (int kb = 0; kb < 8; ++kb) {
        bf16x8 ah[4];
        int koff = kb * 32 + lk * 8;
        #pragma unroll
        for (int m = 0; m < 4; ++m) {
            int row = m * 16 + l16;
            int byte = ((row * CIN + koff) * 2) ^ ((row & 7) << 4);
            ah[m] = *reinterpret_cast<const bf16x8*>(AhiB + byte);
        }
        // --- Z unit (half0): steady-state outstanding = {Z(kb),H(kb)} = 4 loads ---
        if (kb >= 1) asm volatile("s_waitcnt vmcnt(2)" ::: "memory");   // Z(kb) arrived
        bf16x8 zb0 = *reinterpret_cast<const bf16x8*>(wbuf + lane * 16);
        bf16x8 zb1 = *reinterpret_cast<const bf16x8*>(wbuf + 1024 + lane * 16);
        asm volatile("s_waitcnt lgkmcnt(0)" ::: "memory");              // zb in VGPRs before overwrite
        if (kb < 7) stage_gate(kb + 1, 0);
        #pragma unroll
        for (int m = 0; m < 4; ++m) {
            accZ[0][m] = mfma16(ah[m], zb0, accZ[0][m]);
            accZ[1][m] = mfma16(ah[m], zb1, accZ[1][m]);
        }
        // --- H unit (half1) ---
        if (kb == 7)      asm volatile("s_waitcnt vmcnt(0)" ::: "memory");  // no trailing stage
        else if (kb >= 1) asm volatile("s_waitcnt vmcnt(2)" ::: "memory");  // H(kb) arrived
        bf16x8 hb0 = *reinterpret_cast<const bf16x8*>(wbuf + 2048 + lane * 16);
        bf16x8 hb1 = *reinterpret_cast<const bf16x8*>(wbuf + 3072 + lane * 16);
        asm volatile("s_waitcnt lgkmcnt(0)" ::: "memory");
        if (kb < 7) stage_gate(kb + 1, 1);
        #pragma unroll
        for (int m = 0; m < 4; ++m) {
            accH[0][m] = mfma16(ah[m], hb0, accH[0][m]);
            accH[1][m] = mfma16(ah[m], hb1, accH[1][m]);
        }
    }
    // issue first out-weight load (global->VGPR) before the barrier
    bf16x8 cb = ldfrag(wf, 256 + (wv & 3) * 8, lane);
    __syncthreads();   // all waves done reading x/dbufs before h overwrites smem

    // ---- nonlinearities + GRU blend; h -> LDS as (bf16 bits << 16) u32 (word stores) ----
    #pragma unroll
    for (int nfi = 0; nfi < 2; ++nfi) {
        int col = wv * 32 + nfi * 16 + l16;
        #pragma unroll
        for (int m = 0; m < 4; ++m) {
            #pragma unroll
            for (int i = 0; i < 4; ++i) {
                float z  = 1.f / (1.f + __expf(-(accZ[nfi][m][i] + bzv[nfi])));
                float tt = __expf(2.f * (accH[nfi][m][i] + bhv[nfi]));
                float th = (tt - 1.f) / (tt + 1.f);
                float H  = (1.f - z) * th;
                float h  = (H > 0.f) ? H : (__expf(H) - 1.f);   // elu(alpha=1)
                int row = m * 16 + lk * 4 + i;                  // C/D: row=(lane>>4)*4+reg
                unsigned pk = ((unsigned)f2bf(h)) << 16;
                int byte = (row * 1024 + col * 4) ^ ((row & 7) << 4);  // u32, row stride 1 KB
                *reinterpret_cast<unsigned*>(smem + byte) = pk;
            }
        }
    }
    __syncthreads();   // h visible to all waves

    // ---- out GEMM: wave wv -> rows [mo*32, +32) (2 m-frags), out-cols [(wv&3)*16,+16) ----
    f32x4 accO[2];
    accO[0] = (f32x4){0.f, 0.f, 0.f, 0.f};
    accO[1] = (f32x4){0.f, 0.f, 0.f, 0.f};
    for (int kb = 0; kb < 8; ++kb) {
        int nk = kb < 7 ? kb + 1 : 7;
        bf16x8 nb = ldfrag(wf, 256 + (wv & 3) * 8 + nk, lane);    // depth-1 prefetch
        #pragma unroll
        for (int m = 0; m < 2; ++m) {
            int row = mo * 32 + m * 16 + l16;
            int e0  = kb * 32 + lk * 8;
            int b0  = (row * 1024 + e0 * 4)      ^ ((row & 7) << 4);
            int b1  = (row * 1024 + e0 * 4 + 16) ^ ((row & 7) << 4);
            uint4 p0 = *reinterpret_cast<const uint4*>(smem + b0);
            uint4 p1 = *reinterpret_cast<const uint4*>(smem + b1);
            bf16x8 ha;
            ha[0] = (short)(p0.x >> 16); ha[1] = (short)(p0.y >> 16);
            ha[2] = (short)(p0.z >> 16); ha[3] = (short)(p0.w >> 16);
            ha[4] = (short)(p1.x >> 16); ha[5] = (short)(p1.y >> 16);
            ha[6] = (short)(p1.z >> 16); ha[7] = (short)(p1.w >> 16);
            accO[m] = mfma16(ha, cb, accO[m]);
        }
        cb = nb;
    }
    #pragma unroll
    for (int m = 0; m < 2; ++m)
        #pragma unroll
        for (int i = 0; i < 4; ++i) {
            int row = row0 + mo * 32 + m * 16 + lk * 4 + i;
            if (row < N_ROWS) out[(size_t)row * COUT + ocol] = accO[m][i] + bo;
        }
}

// ---------------- fallback: round-2 f32 kernel (proven; used only if ws too small) ----------------
__global__ __launch_bounds__(256) void fallback_f32(
    const float* __restrict__ x, const float* __restrict__ mask,
    const float* __restrict__ wzr, const float* __restrict__ whr,
    const float* __restrict__ bz, const float* __restrict__ bh,
    const float* __restrict__ wlinr, const float* __restrict__ blin,
    float* __restrict__ out)
{
    __shared__ float xm[32][CIN];
    const int tid = threadIdx.x;
    const int row0 = blockIdx.x * 32;
    #pragma unroll
    for (int it = 0; it < 8; ++it) {
        int idx = it * 256 + tid;
        int r = idx >> 6, c4 = idx & 63, row = row0 + r;
        float4 v = make_float4(0.f, 0.f, 0.f, 0.f);
        if (row < N_ROWS) {
            float4 a = reinterpret_cast<const float4*>(x    + (size_t)row * CIN)[c4];
            float4 m = reinterpret_cast<const float4*>(mask + (size_t)row * CIN)[c4];
            v = make_float4(a.x * m.x, a.y * m.y, a.z * m.z, a.w * m.w);
        }
        reinterpret_cast<float4*>(&xm[r][0])[c4] = v;
    }
    __syncthreads();
    const int j0 = (tid & 63) * 4, r0 = (tid >> 6) * 8;
    float accz[4][8], acch[4][8];
    #pragma unroll
    for (int c = 0; c < 4; ++c)
        #pragma unroll
        for (int r = 0; r < 8; ++r) { accz[c][r] = 0.f; acch[c][r] = 0.f; }
    for (int k = 0; k < CIN; k += 4) {
        float4 wz4[4], wh4[4];
        #pragma unroll
        for (int kk = 0; kk < 4; ++kk) {
            float4 a0 = *reinterpret_cast<const float4*>(&wzr[(k + kk) * 256 + j0]);
            float4 a1 = *reinterpret_cast<const float4*>(&wzr[131072 + (k + kk) * 256 + j0]);
            wz4[kk] = make_float4(a0.x + a1.x, a0.y + a1.y, a0.z + a1.z, a0.w + a1.w);
            float4 b0 = *reinterpret_cast<const float4*>(&whr[(k + kk) * 256 + j0]);
            float4 b1 = *reinterpret_cast<const float4*>(&whr[131072 + (k + kk) * 256 + j0]);
            wh4[kk] = make_float4(b0.x + b1.x, b0.y + b1.y, b0.z + b1.z, b0.w + b1.w);
        }
        #pragma unroll
        for (int r = 0; r < 8; ++r) {
            float4 xv = *reinterpret_cast<const float4*>(&xm[r0 + r][k]);
            float xk[4] = {xv.x, xv.y, xv.z, xv.w};
            float wzc[4][4] = {{wz4[0].x,wz4[0].y,wz4[0].z,wz4[0].w},{wz4[1].x,wz4[1].y,wz4[1].z,wz4[1].w},
                               {wz4[2].x,wz4[2].y,wz4[2].z,wz4[2].w},{wz4[3].x,wz4[3].y,wz4[3].z,wz4[3].w}};
            float whc[4][4] = {{wh4[0].x,wh4[0].y,wh4[0].z,wh4[0].w},{wh4[1].x,wh4[1].y,wh4[1].z,wh4[1].w},
                               {wh4[2].x,wh4[2].y,wh4[2].z,wh4[2].w},{wh4[3].x,wh4[3].y,wh4[3].z,wh4[3].w}};
            #pragma unroll
            for (int kk = 0; kk < 4; ++kk)
                #pragma unroll
                for (int c = 0; c < 4; ++c) {
                    accz[c][r] = fmaf(xk[kk], wzc[kk][c], accz[c][r]);
                    acch[c][r] = fmaf(xk[kk], whc[kk][c], acch[c][r]);
                }
        }
    }
    float bzj[4], bhj[4];
    #pragma unroll
    for (int c = 0; c < 4; ++c) { bzj[c] = bz[j0 + c]; bhj[c] = bh[j0 + c]; }
    __syncthreads();
    #pragma unroll
    for (int r = 0; r < 8; ++r) {
        float hc[4];
        #pragma unroll
        for (int c = 0; c < 4; ++c) {
            float z  = 1.f / (1.f + expf(-(accz[c][r] + bzj[c])));
            float ht = tanhf(acch[c][r] + bhj[c]);
            float H  = (1.f - z) * ht;
            hc[c] = (H > 0.f) ? H : expm1f(H);
        }
        *reinterpret_cast<float4*>(&xm[r0 + r][j0]) = make_float4(hc[0], hc[1], hc[2], hc[3]);
    }
    __syncthreads();
    const int o = tid & 63;
    float acc[8];
    #pragma unroll
    for (int r = 0; r < 8; ++r) acc[r] = 0.f;
    for (int k = 0; k < CIN; k += 4) {
        float4 wv4 = *reinterpret_cast<const float4*>(&wlinr[o * 256 + k]);
        #pragma unroll
        for (int r = 0; r < 8; ++r) {
            float4 hv = *reinterpret_cast<const float4*>(&xm[r0 + r][k]);
            acc[r] = fmaf(hv.x, wv4.x, acc[r]);
            acc[r] = fmaf(hv.y, wv4.y, acc[r]);
            acc[r] = fmaf(hv.z, wv4.z, acc[r]);
            acc[r] = fmaf(hv.w, wv4.w, acc[r]);
        }
    }
    float bo = blin[o];
    #pragma unroll
    for (int r = 0; r < 8; ++r) {
        int row = row0 + r0 + r;
        if (row < N_ROWS) out[(size_t)row * COUT + o] = acc[r] + bo;
    }
}

extern "C" void kernel_launch(void* const* d_in, const int* in_sizes, int n_in,
                              void* d_out, int out_size, void* d_ws, size_t ws_size,
                              hipStream_t stream)
{
    const float* x    = (const float*)d_in[0];
    // d_in[1] edge_index, d_in[2] edge_weight: unused (K=1 identity term only)
    const float* mask = (const float*)d_in[3];
    const float* wz   = (const float*)d_in[4];
    const float* bz   = (const float*)d_in[5];
    // d_in[6] w_r, d_in[7] b_r: dead (H=0 -> reset gate unused)
    const float* wh   = (const float*)d_in[8];
    const float* bh   = (const float*)d_in[9];
    const float* wlin = (const float*)d_in[10];
    const float* blin = (const float*)d_in[11];
    float* outf = (float*)d_out;

    const size_t ws_need = 288 * 1024;   // 288 frags x 1 KB
    if (ws_size >= ws_need) {
        unsigned short* wsf = (unsigned short*)d_ws;
        prep_frags<<<72, 256, 0, stream>>>(wz, wh, wlin, wsf);
        dcrnn_async<<<(N_ROWS + BM - 1) / BM, 512, 0, stream>>>(
            x, mask, wsf, bz, bh, blin, outf);
    } else {
        fallback_f32<<<(N_ROWS + 31) / 32, 256, 0, stream>>>(
            x, mask, wz, wh, bz, bh, wlin, blin, outf);
    }
}